// Round 5
// baseline (411.020 us; speedup 1.0000x reference)
//
#include <hip/hip_runtime.h>
#include <cstdint>
#include <cstddef>

#define N_NODES 100000
#define E_EDGES 1600000
#define HCH 128
#define NHEADS 8
#define HDIM 16

typedef unsigned int uint;
typedef unsigned short ushort;
typedef __attribute__((ext_vector_type(8))) short short8;
typedef __attribute__((ext_vector_type(4))) float floatx4;
typedef __attribute__((ext_vector_type(2))) float floatx2;

__device__ __forceinline__ ushort f2bf(float f) {
    uint u = __float_as_uint(f);
    u = (u + 0x7fff + ((u >> 16) & 1)) >> 16;
    return (ushort)u;
}
__device__ __forceinline__ float bflo(uint p) { return __uint_as_float(p << 16); }
__device__ __forceinline__ float bfhi(uint p) { return __uint_as_float(p & 0xffff0000u); }

// ============ prep_w: fp32 [K][N] -> bf16 [N][K] fragment layout ============
// wq rows 0-127 (from Wq); wkv rows 0-127 = Wk, 128-255 = Wv; wo rows 0-127 (Wo).
// Strided reads are L2-served after first touch (whole W set = 256 KB).
__global__ __launch_bounds__(256) void prep_w(
    const float* __restrict__ Wq, const float* __restrict__ Wk,
    const float* __restrict__ Wv, const float* __restrict__ Wo,
    ushort* __restrict__ wq_bf, ushort* __restrict__ wkv_bf, ushort* __restrict__ wo_bf)
{
    const int t = threadIdx.x;
    int r = blockIdx.x * 16 + (t >> 4);   // 0..511 global output row
    int k0 = (t & 15) * 8;
    const float* W; ushort* o; int n, orow;
    if (r < 128)      { W = Wq; o = wq_bf;  n = r;       orow = r; }
    else if (r < 256) { W = Wk; o = wkv_bf; n = r - 128; orow = r - 128; }
    else if (r < 384) { W = Wv; o = wkv_bf; n = r - 256; orow = r - 128; }
    else              { W = Wo; o = wo_bf;  n = r - 384; orow = r - 384; }
    uint4 u;
    u.x = (uint)f2bf(W[(size_t)(k0 + 0) * HCH + n]) | ((uint)f2bf(W[(size_t)(k0 + 1) * HCH + n]) << 16);
    u.y = (uint)f2bf(W[(size_t)(k0 + 2) * HCH + n]) | ((uint)f2bf(W[(size_t)(k0 + 3) * HCH + n]) << 16);
    u.z = (uint)f2bf(W[(size_t)(k0 + 4) * HCH + n]) | ((uint)f2bf(W[(size_t)(k0 + 5) * HCH + n]) << 16);
    u.w = (uint)f2bf(W[(size_t)(k0 + 6) * HCH + n]) | ((uint)f2bf(W[(size_t)(k0 + 7) * HCH + n]) << 16);
    *(uint4*)(o + (size_t)orow * HCH + k0) = u;
}

// ============ gemm_qkv: y=0 -> q (N=128), y=1 -> [k|v] (N=256) ============
// B-fragments loaded directly from global (no LDS weight staging).
// Cs (bf16) aliases As. kv epilogue writes full 256B rows (no write amp).
// kv row layout per 16B chunk sub: bytes [0,8)=k[8sub..8sub+8), [8,16)=v[...].
__global__ __launch_bounds__(256) void gemm_qkv(
    const float* __restrict__ A,
    const ushort* __restrict__ wq_bf, const ushort* __restrict__ wkv_bf,
    const float* __restrict__ bq, const float* __restrict__ bk, const float* __restrict__ bv,
    unsigned char* __restrict__ qe, unsigned char* __restrict__ kvb,
    int M)
{
    __shared__ __align__(16) char smem[64 * 264 * 2];     // 33792 B
    ushort (*As)[136] = (ushort(*)[136])smem;             // A tile 64x128 bf16 (+pad)
    ushort (*Cs)[264] = (ushort(*)[264])smem;             // aliased after sync

    const int t = threadIdx.x;
    const int mb = blockIdx.x * 64;
    const bool kvmode = (blockIdx.y != 0);

    // stage A tile (fp32 -> bf16)
#pragma unroll
    for (int i = 0; i < 8; i++) {
        int p = t + i * 256;
        int row = p >> 5, c4 = p & 31;
        int g = mb + row;
        float4 a4 = make_float4(0.f, 0.f, 0.f, 0.f);
        if (g < M) a4 = *(const float4*)(A + (size_t)g * HCH + c4 * 4);
        uint lo = (uint)f2bf(a4.x) | ((uint)f2bf(a4.y) << 16);
        uint hi = (uint)f2bf(a4.z) | ((uint)f2bf(a4.w) << 16);
        *(uint2*)(&As[row][c4 * 4]) = make_uint2(lo, hi);
    }
    __syncthreads();

    const int lane = t & 63;
    const int w = t >> 6;
    const int m_l = lane & 15;
    const int q_l = lane >> 4;

    if (!kvmode) {
        floatx4 acc[8];
#pragma unroll
        for (int tl = 0; tl < 8; tl++) acc[tl] = (floatx4){0.f, 0.f, 0.f, 0.f};
#pragma unroll
        for (int ks = 0; ks < 4; ks++) {
            short8 af = *(const short8*)(&As[w * 16 + m_l][ks * 32 + q_l * 8]);
            const ushort* wb = wq_bf + (size_t)m_l * HCH + ks * 32 + q_l * 8;
#pragma unroll
            for (int tl = 0; tl < 8; tl++) {
                short8 bf = *(const short8*)(wb + (size_t)tl * 16 * HCH);
                acc[tl] = __builtin_amdgcn_mfma_f32_16x16x32_bf16(af, bf, acc[tl], 0, 0, 0);
            }
        }
        __syncthreads();
#pragma unroll
        for (int tl = 0; tl < 8; tl++)
#pragma unroll
            for (int r = 0; r < 4; r++)
                Cs[w * 16 + q_l * 4 + r][tl * 16 + m_l] = f2bf(acc[tl][r]);
        __syncthreads();
        // epilogue q: full 128B rows, 16 uint2 per row
#pragma unroll
        for (int i = 0; i < 4; i++) {
            int p = t + i * 256;
            int row = p >> 4, u = p & 15;
            int g = mb + row;
            if (g >= M) continue;
            uint4 c = *(const uint4*)(&Cs[row][u * 8]);
            float4 b0 = *(const float4*)(bq + u * 8);
            float4 b1 = *(const float4*)(bq + u * 8 + 4);
            int r0 = __builtin_amdgcn_cvt_pk_fp8_f32(bflo(c.x) + b0.x, bfhi(c.x) + b0.y, 0, false);
            r0 = __builtin_amdgcn_cvt_pk_fp8_f32(bflo(c.y) + b0.z, bfhi(c.y) + b0.w, r0, true);
            int r1 = __builtin_amdgcn_cvt_pk_fp8_f32(bflo(c.z) + b1.x, bfhi(c.z) + b1.y, 0, false);
            r1 = __builtin_amdgcn_cvt_pk_fp8_f32(bflo(c.w) + b1.z, bfhi(c.w) + b1.w, r1, true);
            *(uint2*)(qe + (size_t)g * 128 + u * 8) = make_uint2((uint)r0, (uint)r1);
        }
    } else {
        floatx4 acc[16];
#pragma unroll
        for (int tl = 0; tl < 16; tl++) acc[tl] = (floatx4){0.f, 0.f, 0.f, 0.f};
#pragma unroll
        for (int ks = 0; ks < 4; ks++) {
            short8 af = *(const short8*)(&As[w * 16 + m_l][ks * 32 + q_l * 8]);
            const ushort* wb = wkv_bf + (size_t)m_l * HCH + ks * 32 + q_l * 8;
#pragma unroll
            for (int tl = 0; tl < 16; tl++) {
                short8 bf = *(const short8*)(wb + (size_t)tl * 16 * HCH);
                acc[tl] = __builtin_amdgcn_mfma_f32_16x16x32_bf16(af, bf, acc[tl], 0, 0, 0);
            }
        }
        __syncthreads();
#pragma unroll
        for (int tl = 0; tl < 16; tl++)
#pragma unroll
            for (int r = 0; r < 4; r++)
                Cs[w * 16 + q_l * 4 + r][tl * 16 + m_l] = f2bf(acc[tl][r]);
        __syncthreads();
        // epilogue kv: full 256B rows, 32 uint2 per row; cols 0-127 = k, 128-255 = v
#pragma unroll
        for (int i = 0; i < 8; i++) {
            int p = t + i * 256;
            int row = p >> 5, u = p & 31;
            int g = mb + row;
            if (g >= M) continue;
            int sub = u >> 1, half = u & 1;
            int col0 = half * 128 + sub * 8;
            uint4 c = *(const uint4*)(&Cs[row][col0]);
            const float* bb = half ? bv : bk;
            float4 b0 = *(const float4*)(bb + sub * 8);
            float4 b1 = *(const float4*)(bb + sub * 8 + 4);
            int r0 = __builtin_amdgcn_cvt_pk_fp8_f32(bflo(c.x) + b0.x, bfhi(c.x) + b0.y, 0, false);
            r0 = __builtin_amdgcn_cvt_pk_fp8_f32(bflo(c.y) + b0.z, bfhi(c.y) + b0.w, r0, true);
            int r1 = __builtin_amdgcn_cvt_pk_fp8_f32(bflo(c.z) + b1.x, bfhi(c.z) + b1.y, 0, false);
            r1 = __builtin_amdgcn_cvt_pk_fp8_f32(bflo(c.w) + b1.z, bfhi(c.w) + b1.w, r1, true);
            *(uint2*)(kvb + (size_t)g * 256 + u * 8) = make_uint2((uint)r0, (uint)r1);
        }
    }
}

// ============ gemm_out: out = x + (attended * invL[head]) @ Wo + bo ============
__global__ __launch_bounds__(256) void gemm_out(
    const ushort* __restrict__ A, const ushort* __restrict__ wo_bf,
    const float* __restrict__ bias, const float* __restrict__ res,
    const float* __restrict__ head_invl,
    float* __restrict__ C, int M)
{
    __shared__ __align__(16) char smem[64 * 136 * 2];     // 17408 B
    ushort (*As)[136] = (ushort(*)[136])smem;
    ushort (*Cs)[136] = (ushort(*)[136])smem;             // aliased after sync

    const int t = threadIdx.x;
    const int mb = blockIdx.x * 64;

    __shared__ float invl_s[8];
    if (t < 8) invl_s[t] = head_invl[t];
    __syncthreads();

#pragma unroll
    for (int i = 0; i < 8; i++) {
        int p = t + i * 256;
        int row = p >> 5, cu2 = p & 31;
        int g = mb + row;
        uint2 a = make_uint2(0, 0);
        if (g < M) a = *(const uint2*)(A + (size_t)g * HCH + cu2 * 4);
        float invl = invl_s[cu2 >> 2];
        float f0 = bflo(a.x) * invl, f1 = bfhi(a.x) * invl;
        float f2 = bflo(a.y) * invl, f3 = bfhi(a.y) * invl;
        uint lo = (uint)f2bf(f0) | ((uint)f2bf(f1) << 16);
        uint hi = (uint)f2bf(f2) | ((uint)f2bf(f3) << 16);
        *(uint2*)(&As[row][cu2 * 4]) = make_uint2(lo, hi);
    }
    __syncthreads();

    const int lane = t & 63;
    const int w = t >> 6;
    const int m_l = lane & 15;
    const int q_l = lane >> 4;

    floatx4 acc[8];
#pragma unroll
    for (int tl = 0; tl < 8; tl++) acc[tl] = (floatx4){0.f, 0.f, 0.f, 0.f};
#pragma unroll
    for (int ks = 0; ks < 4; ks++) {
        short8 af = *(const short8*)(&As[w * 16 + m_l][ks * 32 + q_l * 8]);
        const ushort* wb = wo_bf + (size_t)m_l * HCH + ks * 32 + q_l * 8;
#pragma unroll
        for (int tl = 0; tl < 8; tl++) {
            short8 bf = *(const short8*)(wb + (size_t)tl * 16 * HCH);
            acc[tl] = __builtin_amdgcn_mfma_f32_16x16x32_bf16(af, bf, acc[tl], 0, 0, 0);
        }
    }
    __syncthreads();
#pragma unroll
    for (int tl = 0; tl < 8; tl++)
#pragma unroll
        for (int r = 0; r < 4; r++)
            Cs[w * 16 + q_l * 4 + r][tl * 16 + m_l] = f2bf(acc[tl][r]);
    __syncthreads();

#pragma unroll
    for (int i = 0; i < 8; i++) {
        int p = t + i * 256;
        int row = p >> 5, u = p & 31;      // 32 float4 per 128-ch row
        int g = mb + row;
        if (g >= M) continue;
        uint2 c = *(const uint2*)(&Cs[row][u * 4]);
        float4 b4 = *(const float4*)(bias + u * 4);
        float4 r4 = *(const float4*)(res + (size_t)g * HCH + u * 4);
        float4 o;
        o.x = bflo(c.x) + b4.x + r4.x;
        o.y = bfhi(c.x) + b4.y + r4.y;
        o.z = bflo(c.y) + b4.z + r4.z;
        o.w = bfhi(c.y) + b4.w + r4.w;
        *(float4*)(C + (size_t)g * HCH + u * 4) = o;
    }
}

// ================= two-pass bucketed counting sort by dst =================
constexpr int BSHIFT = 8;
constexpr int NBUCK  = ((N_NODES - 1) >> BSHIFT) + 1;   // 391
constexpr int S1_GRID = 256;
constexpr int S1_CH   = (E_EDGES + S1_GRID - 1) / S1_GRID;  // 6250
constexpr int S2_CAP  = 6144;

__global__ __launch_bounds__(256) void bucket_hist(
    const int* __restrict__ dst, int* __restrict__ bucket_total)
{
    __shared__ int cnt[NBUCK];
    const int t = threadIdx.x;
    for (int b = t; b < NBUCK; b += 256) cnt[b] = 0;
    __syncthreads();
    const int e0 = blockIdx.x * S1_CH;
    const int n = min(S1_CH, E_EDGES - e0);
    for (int i = t; i < n; i += 256)
        atomicAdd(&cnt[dst[e0 + i] >> BSHIFT], 1);
    __syncthreads();
    for (int b = t; b < NBUCK; b += 256)
        if (cnt[b]) atomicAdd(&bucket_total[b], cnt[b]);
}

__global__ __launch_bounds__(512) void bucket_scan(
    const int* __restrict__ bucket_total, int* __restrict__ bucket_start,
    int* __restrict__ bucket_cursor, int* __restrict__ offsets)
{
    __shared__ int s[512];
    const int t = threadIdx.x;
    int v = (t < NBUCK) ? bucket_total[t] : 0;
    s[t] = v;
    __syncthreads();
    for (int off = 1; off < 512; off <<= 1) {
        int a = (t >= off) ? s[t - off] : 0;
        __syncthreads();
        s[t] += a;
        __syncthreads();
    }
    int excl = s[t] - v;
    if (t < NBUCK) { bucket_start[t] = excl; bucket_cursor[t] = excl; }
    if (t == 0) { bucket_start[NBUCK] = E_EDGES; offsets[N_NODES] = E_EDGES; }
}

__global__ __launch_bounds__(256) void sort_scatter1(
    const int* __restrict__ src, const int* __restrict__ dst,
    int* __restrict__ bucket_cursor, int2* __restrict__ tmp)
{
    __shared__ int ls[S1_CH];
    __shared__ int ld[S1_CH];
    __shared__ int cnt[NBUCK];
    const int t = threadIdx.x;
    for (int b = t; b < NBUCK; b += 256) cnt[b] = 0;
    __syncthreads();
    const int e0 = blockIdx.x * S1_CH;
    const int n = min(S1_CH, E_EDGES - e0);
    for (int i = t; i < n; i += 256) {
        int d = dst[e0 + i];
        ls[i] = src[e0 + i];
        ld[i] = d;
        atomicAdd(&cnt[d >> BSHIFT], 1);
    }
    __syncthreads();
    for (int b = t; b < NBUCK; b += 256) {
        int c = cnt[b];
        cnt[b] = c ? atomicAdd(&bucket_cursor[b], c) : 0;
    }
    __syncthreads();
    for (int i = t; i < n; i += 256) {
        int d = ld[i];
        int pos = atomicAdd(&cnt[d >> BSHIFT], 1);
        tmp[pos] = make_int2(ls[i], d);
    }
}

__global__ __launch_bounds__(256) void sort_scatter2(
    const int2* __restrict__ tmp, const int* __restrict__ bucket_start,
    int* __restrict__ psrc, int* __restrict__ offsets)
{
    __shared__ int2 le[S2_CAP];
    __shared__ int cnt[256];
    __shared__ int s[256];
    __shared__ int cur[256];
    const int t = threadIdx.x;
    const int b = blockIdx.x;
    const int bstart = bucket_start[b];
    const int n = bucket_start[b + 1] - bstart;
    cnt[t] = 0;
    __syncthreads();
    for (int i = t; i < n; i += 256) {
        int2 e = tmp[bstart + i];
        if (i < S2_CAP) le[i] = e;
        atomicAdd(&cnt[e.y & 255], 1);
    }
    __syncthreads();
    int v = cnt[t];
    s[t] = v;
    __syncthreads();
    for (int off = 1; off < 256; off <<= 1) {
        int a = (t >= off) ? s[t - off] : 0;
        __syncthreads();
        s[t] += a;
        __syncthreads();
    }
    int excl = s[t] - v;
    int node = (b << BSHIFT) + t;
    if (node < N_NODES) offsets[node] = bstart + excl;
    cur[t] = excl;
    __syncthreads();
    for (int i = t; i < n; i += 256) {
        int2 e = (i < S2_CAP) ? le[i] : tmp[bstart + i];
        int pos = bstart + atomicAdd(&cur[e.y & 255], 1);
        psrc[pos] = e.x;
    }
}

// ============ FUSED segment reduce: ONE NODE PER 16-LANE GROUP ============
constexpr int FU_BLOCKS = 2048;
constexpr int FU_GROUPS = FU_BLOCKS * 16;

__device__ __forceinline__ float edge_w(
    uint4 e, floatx2 q0, floatx2 q1, floatx2 q2, floatx2 q3)
{
    floatx2 dp = q0 * __builtin_amdgcn_cvt_pk_f32_fp8((int)e.x, false);
    dp += q1 * __builtin_amdgcn_cvt_pk_f32_fp8((int)e.x, true);
    dp += q2 * __builtin_amdgcn_cvt_pk_f32_fp8((int)e.y, false);
    dp += q3 * __builtin_amdgcn_cvt_pk_f32_fp8((int)e.y, true);
    float p = dp.x + dp.y;
    p += __shfl_xor(p, 1);
    return __expf(p * 0.25f);
}
__device__ __forceinline__ void edge_acc(
    uint4 e, float wgt, floatx2& a01, floatx2& a23, floatx2& a45, floatx2& a67)
{
    floatx2 wv = {wgt, wgt};
    a01 += wv * __builtin_amdgcn_cvt_pk_f32_fp8((int)e.z, false);
    a23 += wv * __builtin_amdgcn_cvt_pk_f32_fp8((int)e.z, true);
    a45 += wv * __builtin_amdgcn_cvt_pk_f32_fp8((int)e.w, false);
    a67 += wv * __builtin_amdgcn_cvt_pk_f32_fp8((int)e.w, true);
}

__global__ __launch_bounds__(256) void edge_fused(
    const unsigned char* __restrict__ qe, const unsigned char* __restrict__ kv,
    const int* __restrict__ psrc, const int* __restrict__ offsets,
    ushort* __restrict__ attended, float* __restrict__ block_l)
{
    const int t = threadIdx.x;
    const int sub = t & 15;
    const int gg0 = blockIdx.x * 16 + (t >> 4);

    float lsum = 0.f;

    for (int d = gg0; d < N_NODES; d += FU_GROUPS) {
        const int start = offsets[d];
        const int end   = offsets[d + 1];

        uint2 qw = *(const uint2*)(qe + (size_t)d * 128 + sub * 8);
        floatx2 q0 = __builtin_amdgcn_cvt_pk_f32_fp8((int)qw.x, false);
        floatx2 q1 = __builtin_amdgcn_cvt_pk_f32_fp8((int)qw.x, true);
        floatx2 q2 = __builtin_amdgcn_cvt_pk_f32_fp8((int)qw.y, false);
        floatx2 q3 = __builtin_amdgcn_cvt_pk_f32_fp8((int)qw.y, true);

        floatx2 a01 = {0.f, 0.f}, a23 = {0.f, 0.f}, a45 = {0.f, 0.f}, a67 = {0.f, 0.f};

        for (int i = start; i < end; i += 4) {
            int i1 = min(i + 1, end - 1);
            int i2 = min(i + 2, end - 1);
            int i3 = min(i + 3, end - 1);
            int s0 = psrc[i];
            int s1 = psrc[i1];
            int s2 = psrc[i2];
            int s3 = psrc[i3];
            uint4 e0 = *(const uint4*)(kv + (size_t)s0 * 256 + sub * 16);
            uint4 e1 = *(const uint4*)(kv + (size_t)s1 * 256 + sub * 16);
            uint4 e2 = *(const uint4*)(kv + (size_t)s2 * 256 + sub * 16);
            uint4 e3 = *(const uint4*)(kv + (size_t)s3 * 256 + sub * 16);

            float w0 = edge_w(e0, q0, q1, q2, q3);
            float w1 = edge_w(e1, q0, q1, q2, q3);
            float w2 = edge_w(e2, q0, q1, q2, q3);
            float w3 = edge_w(e3, q0, q1, q2, q3);
            if (i + 1 >= end) w1 = 0.f;
            if (i + 2 >= end) w2 = 0.f;
            if (i + 3 >= end) w3 = 0.f;
            lsum += w0 + w1 + w2 + w3;

            edge_acc(e0, w0, a01, a23, a45, a67);
            edge_acc(e1, w1, a01, a23, a45, a67);
            edge_acc(e2, w2, a01, a23, a45, a67);
            edge_acc(e3, w3, a01, a23, a45, a67);
        }

        uint4 o;
        o.x = (uint)f2bf(a01.x) | ((uint)f2bf(a01.y) << 16);
        o.y = (uint)f2bf(a23.x) | ((uint)f2bf(a23.y) << 16);
        o.z = (uint)f2bf(a45.x) | ((uint)f2bf(a45.y) << 16);
        o.w = (uint)f2bf(a67.x) | ((uint)f2bf(a67.y) << 16);
        *(uint4*)(attended + (size_t)d * HCH + sub * 8) = o;
    }

    __shared__ float sl[256];
    sl[t] = lsum;
    __syncthreads();
    if (t < 8) {
        float L = 0.f;
        for (int base = 0; base < 256; base += 16)
            L += sl[base + 2 * t] + sl[base + 2 * t + 1];
        block_l[blockIdx.x * 8 + t] = 0.5f * L;
    }
}

__global__ __launch_bounds__(256) void reduce_l(
    const float* __restrict__ block_l, float* __restrict__ head_invl, int nblk)
{
    const int t = threadIdx.x;
    float l = 0.f;
    for (int i = t; i < nblk * 8; i += 256) l += block_l[i];
    __shared__ float sl[256];
    sl[t] = l;
    __syncthreads();
    if (t < 8) {
        float L = 0.f;
        for (int i = t; i < 256; i += 8) L += sl[i];
        head_invl[t] = 1.0f / L;
    }
}

extern "C" void kernel_launch(void* const* d_in, const int* in_sizes, int n_in,
                              void* d_out, int out_size, void* d_ws, size_t ws_size,
                              hipStream_t stream)
{
    const float* x  = (const float*)d_in[0];
    const int* eidx = (const int*)d_in[1];
    const float* Wq = (const float*)d_in[2];
    const float* bq = (const float*)d_in[3];
    const float* Wk = (const float*)d_in[4];
    const float* bk = (const float*)d_in[5];
    const float* Wv = (const float*)d_in[6];
    const float* bv = (const float*)d_in[7];
    const float* Wo = (const float*)d_in[8];
    const float* bo = (const float*)d_in[9];
    float* out = (float*)d_out;

    char* ws = (char*)d_ws;
    constexpr size_t SZ_Q8  = (size_t)N_NODES * HCH;          // 12.8 MB fp8 q
    constexpr size_t SZ_KV8 = (size_t)N_NODES * HCH * 2;      // 25.6 MB fp8 kv interleaved
    constexpr size_t SZ_ATT = (size_t)N_NODES * HCH * 2;      // 25.6 MB bf16 attended
    constexpr size_t SZ_PS  = (size_t)E_EDGES * sizeof(int);  // 6.4 MB
    constexpr size_t SZ_TMP = (size_t)E_EDGES * sizeof(int2); // 12.8 MB
    size_t off = 0;
    unsigned char* qe  = (unsigned char*)(ws + off); off += SZ_Q8;
    unsigned char* kvb = (unsigned char*)(ws + off); off += SZ_KV8;
    ushort* attended = (ushort*)(ws + off); off += SZ_ATT;
    int*    psrc     = (int*)(ws + off);    off += SZ_PS;
    int2*   tmp      = (int2*)(ws + off);   off += SZ_TMP;
    int*    offsets  = (int*)(ws + off);    off += ((size_t)N_NODES + 1) * 4 + 8;
    int*    bucket_total  = (int*)(ws + off); off += (NBUCK + 1) * 4;
    int*    bucket_start  = (int*)(ws + off); off += (NBUCK + 1) * 4;
    int*    bucket_cursor = (int*)(ws + off); off += (NBUCK + 1) * 4;
    float*  block_l   = (float*)(ws + off); off += (size_t)FU_BLOCKS * 8 * sizeof(float);
    float*  head_invl = (float*)(ws + off); off += 32;
    ushort* wq_bf  = (ushort*)(ws + off); off += (size_t)128 * HCH * 2;
    ushort* wkv_bf = (ushort*)(ws + off); off += (size_t)256 * HCH * 2;
    ushort* wo_bf  = (ushort*)(ws + off); off += (size_t)128 * HCH * 2;
    const int* src = eidx;
    const int* dst = eidx + E_EDGES;

    dim3 blk(256);
    const int gblocks = (N_NODES + 63) / 64;

    prep_w<<<32, blk, 0, stream>>>(Wq, Wk, Wv, Wo, wq_bf, wkv_bf, wo_bf);

    gemm_qkv<<<dim3(gblocks, 2), blk, 0, stream>>>(x, wq_bf, wkv_bf, bq, bk, bv, qe, kvb, N_NODES);

    hipMemsetAsync(bucket_total, 0, (NBUCK + 1) * 4, stream);
    bucket_hist<<<S1_GRID, blk, 0, stream>>>(dst, bucket_total);
    bucket_scan<<<1, 512, 0, stream>>>(bucket_total, bucket_start, bucket_cursor, offsets);
    sort_scatter1<<<S1_GRID, blk, 0, stream>>>(src, dst, bucket_cursor, tmp);
    sort_scatter2<<<NBUCK, blk, 0, stream>>>(tmp, bucket_start, psrc, offsets);

    edge_fused<<<FU_BLOCKS, blk, 0, stream>>>(qe, kvb, psrc, offsets, attended, block_l);
    reduce_l<<<1, blk, 0, stream>>>(block_l, head_invl, FU_BLOCKS);

    gemm_out<<<gblocks, blk, 0, stream>>>(attended, wo_bf, bo, x, head_invl, out, N_NODES);
}

// Round 6
// 335.377 us; speedup vs baseline: 1.2255x; 1.2255x over previous
//
#include <hip/hip_runtime.h>
#include <cstdint>
#include <cstddef>

#define N_NODES 100000
#define E_EDGES 1600000
#define HCH 128
#define NHEADS 8
#define HDIM 16

typedef unsigned int uint;
typedef unsigned short ushort;
typedef __attribute__((ext_vector_type(8))) short short8;
typedef __attribute__((ext_vector_type(4))) float floatx4;
typedef __attribute__((ext_vector_type(2))) float floatx2;

typedef unsigned char uchar;

constexpr int GTILES = (N_NODES + 63) / 64;   // 1563

__device__ __forceinline__ ushort f2bf(float f) {
    uint u = __float_as_uint(f);
    u = (u + 0x7fff + ((u >> 16) & 1)) >> 16;
    return (ushort)u;
}
__device__ __forceinline__ float bflo(uint p) { return __uint_as_float(p << 16); }
__device__ __forceinline__ float bfhi(uint p) { return __uint_as_float(p & 0xffff0000u); }

// ============ prep_w: fp32 [K][N] -> bf16 [N][K]; wall rows: 0-127 Wq, 128-255 Wk,
// 256-383 Wv, 384-511 Wo ============
__global__ __launch_bounds__(256) void prep_w(
    const float* __restrict__ Wq, const float* __restrict__ Wk,
    const float* __restrict__ Wv, const float* __restrict__ Wo,
    ushort* __restrict__ wall)
{
    const int t = threadIdx.x;
    int r = blockIdx.x * 16 + (t >> 4);   // 0..511
    int k0 = (t & 15) * 8;
    const float* W;
    if (r < 128)      W = Wq;
    else if (r < 256) W = Wk;
    else if (r < 384) W = Wv;
    else              W = Wo;
    int n = r & 127;
    uint4 u;
    u.x = (uint)f2bf(W[(size_t)(k0 + 0) * HCH + n]) | ((uint)f2bf(W[(size_t)(k0 + 1) * HCH + n]) << 16);
    u.y = (uint)f2bf(W[(size_t)(k0 + 2) * HCH + n]) | ((uint)f2bf(W[(size_t)(k0 + 3) * HCH + n]) << 16);
    u.z = (uint)f2bf(W[(size_t)(k0 + 4) * HCH + n]) | ((uint)f2bf(W[(size_t)(k0 + 5) * HCH + n]) << 16);
    u.w = (uint)f2bf(W[(size_t)(k0 + 6) * HCH + n]) | ((uint)f2bf(W[(size_t)(k0 + 7) * HCH + n]) << 16);
    *(uint4*)(wall + (size_t)r * HCH + k0) = u;
}

// ============ gemm_qkv: persistent weight-stationary; mode = bid%3 (q/k/v) ============
// Wt staged once per block from wall; grid-stride over A tiles; full 128B fp8 row writes.
__global__ __launch_bounds__(256) void gemm_qkv(
    const float* __restrict__ A, const ushort* __restrict__ wall,
    const float* __restrict__ bq, const float* __restrict__ bk, const float* __restrict__ bv,
    uchar* __restrict__ qe, uchar* __restrict__ kb, uchar* __restrict__ vb,
    int M)
{
    __shared__ __align__(16) ushort Wt[128][136];
    __shared__ __align__(16) char smem[64 * 136 * 2];
    ushort (*As)[136] = (ushort(*)[136])smem;
    ushort (*Cs)[136] = (ushort(*)[136])smem;   // aliased after sync

    const int t = threadIdx.x;
    const int mode = blockIdx.x % 3;
    const int tile0 = blockIdx.x / 3;
    const float* bias;
    uchar* outp;
    if (mode == 0)      { bias = bq; outp = qe; }
    else if (mode == 1) { bias = bk; outp = kb; }
    else                { bias = bv; outp = vb; }

    // stage Wt once (bf16 [n][k], vectorized)
#pragma unroll
    for (int i = 0; i < 8; i++) {
        int p = t + i * 256;
        int row = p >> 4, k0 = (p & 15) * 8;
        *(uint4*)(&Wt[row][k0]) =
            *(const uint4*)(wall + ((size_t)(mode * 128 + row)) * HCH + k0);
    }

    const int lane = t & 63;
    const int w = t >> 6;
    const int m_l = lane & 15;
    const int q_l = lane >> 4;

    for (int tile = tile0; tile < GTILES; tile += 256) {
        const int mb = tile * 64;
        // stage A tile (fp32 -> bf16)
#pragma unroll
        for (int i = 0; i < 8; i++) {
            int p = t + i * 256;
            int row = p >> 5, c4 = p & 31;
            int g = mb + row;
            float4 a4 = make_float4(0.f, 0.f, 0.f, 0.f);
            if (g < M) a4 = *(const float4*)(A + (size_t)g * HCH + c4 * 4);
            uint lo = (uint)f2bf(a4.x) | ((uint)f2bf(a4.y) << 16);
            uint hi = (uint)f2bf(a4.z) | ((uint)f2bf(a4.w) << 16);
            *(uint2*)(&As[row][c4 * 4]) = make_uint2(lo, hi);
        }
        __syncthreads();   // As ready; Wt ready (first iter)

        floatx4 acc[8];
#pragma unroll
        for (int tl = 0; tl < 8; tl++) acc[tl] = (floatx4){0.f, 0.f, 0.f, 0.f};
#pragma unroll
        for (int ks = 0; ks < 4; ks++) {
            short8 af = *(const short8*)(&As[w * 16 + m_l][ks * 32 + q_l * 8]);
#pragma unroll
            for (int tl = 0; tl < 8; tl++) {
                short8 bf = *(const short8*)(&Wt[tl * 16 + m_l][ks * 32 + q_l * 8]);
                acc[tl] = __builtin_amdgcn_mfma_f32_16x16x32_bf16(af, bf, acc[tl], 0, 0, 0);
            }
        }
        __syncthreads();   // all As reads done before Cs overwrite

#pragma unroll
        for (int tl = 0; tl < 8; tl++)
#pragma unroll
            for (int r = 0; r < 4; r++)
                Cs[w * 16 + q_l * 4 + r][tl * 16 + m_l] = f2bf(acc[tl][r]);
        __syncthreads();

        // epilogue: full 128B fp8 rows, 16 uint2 per row
#pragma unroll
        for (int i = 0; i < 4; i++) {
            int p = t + i * 256;
            int row = p >> 4, u = p & 15;
            int g = mb + row;
            if (g < M) {
                uint4 c = *(const uint4*)(&Cs[row][u * 8]);
                float4 b0 = *(const float4*)(bias + u * 8);
                float4 b1 = *(const float4*)(bias + u * 8 + 4);
                int r0 = __builtin_amdgcn_cvt_pk_fp8_f32(bflo(c.x) + b0.x, bfhi(c.x) + b0.y, 0, false);
                r0 = __builtin_amdgcn_cvt_pk_fp8_f32(bflo(c.y) + b0.z, bfhi(c.y) + b0.w, r0, true);
                int r1 = __builtin_amdgcn_cvt_pk_fp8_f32(bflo(c.z) + b1.x, bfhi(c.z) + b1.y, 0, false);
                r1 = __builtin_amdgcn_cvt_pk_fp8_f32(bflo(c.w) + b1.z, bfhi(c.w) + b1.w, r1, true);
                *(uint2*)(outp + (size_t)g * 128 + u * 8) = make_uint2((uint)r0, (uint)r1);
            }
        }
        __syncthreads();   // Cs reads done before next As stage
    }
}

// ============ gemm_out: persistent; out = x + (attended * invL[head]) @ Wo + bo ============
__global__ __launch_bounds__(256) void gemm_out(
    const ushort* __restrict__ A, const ushort* __restrict__ wall,
    const float* __restrict__ bias, const float* __restrict__ res,
    const float* __restrict__ head_invl,
    float* __restrict__ C, int M)
{
    __shared__ __align__(16) ushort Wt[128][136];
    __shared__ __align__(16) char smem[64 * 136 * 2];
    ushort (*As)[136] = (ushort(*)[136])smem;
    ushort (*Cs)[136] = (ushort(*)[136])smem;

    const int t = threadIdx.x;

    __shared__ float invl_s[8];
    if (t < 8) invl_s[t] = head_invl[t];

#pragma unroll
    for (int i = 0; i < 8; i++) {
        int p = t + i * 256;
        int row = p >> 4, k0 = (p & 15) * 8;
        *(uint4*)(&Wt[row][k0]) =
            *(const uint4*)(wall + ((size_t)(384 + row)) * HCH + k0);
    }

    const int lane = t & 63;
    const int w = t >> 6;
    const int m_l = lane & 15;
    const int q_l = lane >> 4;

    for (int tile = blockIdx.x; tile < GTILES; tile += 768) {
        const int mb = tile * 64;
#pragma unroll
        for (int i = 0; i < 8; i++) {
            int p = t + i * 256;
            int row = p >> 5, cu2 = p & 31;
            int g = mb + row;
            uint2 a = make_uint2(0, 0);
            if (g < M) a = *(const uint2*)(A + (size_t)g * HCH + cu2 * 4);
            float invl = invl_s[cu2 >> 2];
            float f0 = bflo(a.x) * invl, f1 = bfhi(a.x) * invl;
            float f2 = bflo(a.y) * invl, f3 = bfhi(a.y) * invl;
            uint lo = (uint)f2bf(f0) | ((uint)f2bf(f1) << 16);
            uint hi = (uint)f2bf(f2) | ((uint)f2bf(f3) << 16);
            *(uint2*)(&As[row][cu2 * 4]) = make_uint2(lo, hi);
        }
        __syncthreads();

        floatx4 acc[8];
#pragma unroll
        for (int tl = 0; tl < 8; tl++) acc[tl] = (floatx4){0.f, 0.f, 0.f, 0.f};
#pragma unroll
        for (int ks = 0; ks < 4; ks++) {
            short8 af = *(const short8*)(&As[w * 16 + m_l][ks * 32 + q_l * 8]);
#pragma unroll
            for (int tl = 0; tl < 8; tl++) {
                short8 bf = *(const short8*)(&Wt[tl * 16 + m_l][ks * 32 + q_l * 8]);
                acc[tl] = __builtin_amdgcn_mfma_f32_16x16x32_bf16(af, bf, acc[tl], 0, 0, 0);
            }
        }
        __syncthreads();

#pragma unroll
        for (int tl = 0; tl < 8; tl++)
#pragma unroll
            for (int r = 0; r < 4; r++)
                Cs[w * 16 + q_l * 4 + r][tl * 16 + m_l] = f2bf(acc[tl][r]);
        __syncthreads();

#pragma unroll
        for (int i = 0; i < 8; i++) {
            int p = t + i * 256;
            int row = p >> 5, u = p & 31;
            int g = mb + row;
            if (g < M) {
                uint2 c = *(const uint2*)(&Cs[row][u * 4]);
                float4 b4 = *(const float4*)(bias + u * 4);
                float4 r4 = *(const float4*)(res + (size_t)g * HCH + u * 4);
                float4 o;
                o.x = bflo(c.x) + b4.x + r4.x;
                o.y = bfhi(c.x) + b4.y + r4.y;
                o.z = bflo(c.y) + b4.z + r4.z;
                o.w = bfhi(c.y) + b4.w + r4.w;
                *(float4*)(C + (size_t)g * HCH + u * 4) = o;
            }
        }
        __syncthreads();
    }
}

// ================= two-pass bucketed counting sort by dst =================
constexpr int BSHIFT = 8;
constexpr int NBUCK  = ((N_NODES - 1) >> BSHIFT) + 1;   // 391
constexpr int S1_GRID = 256;
constexpr int S1_CH   = (E_EDGES + S1_GRID - 1) / S1_GRID;  // 6250
constexpr int S2_CAP  = 6144;

__global__ __launch_bounds__(256) void bucket_hist(
    const int* __restrict__ dst, int* __restrict__ bucket_total)
{
    __shared__ int cnt[NBUCK];
    const int t = threadIdx.x;
    for (int b = t; b < NBUCK; b += 256) cnt[b] = 0;
    __syncthreads();
    const int e0 = blockIdx.x * S1_CH;
    const int n = min(S1_CH, E_EDGES - e0);
    for (int i = t; i < n; i += 256)
        atomicAdd(&cnt[dst[e0 + i] >> BSHIFT], 1);
    __syncthreads();
    for (int b = t; b < NBUCK; b += 256)
        if (cnt[b]) atomicAdd(&bucket_total[b], cnt[b]);
}

__global__ __launch_bounds__(512) void bucket_scan(
    const int* __restrict__ bucket_total, int* __restrict__ bucket_start,
    int* __restrict__ bucket_cursor, int* __restrict__ offsets)
{
    __shared__ int s[512];
    const int t = threadIdx.x;
    int v = (t < NBUCK) ? bucket_total[t] : 0;
    s[t] = v;
    __syncthreads();
    for (int off = 1; off < 512; off <<= 1) {
        int a = (t >= off) ? s[t - off] : 0;
        __syncthreads();
        s[t] += a;
        __syncthreads();
    }
    int excl = s[t] - v;
    if (t < NBUCK) { bucket_start[t] = excl; bucket_cursor[t] = excl; }
    if (t == 0) { bucket_start[NBUCK] = E_EDGES; offsets[N_NODES] = E_EDGES; }
}

__global__ __launch_bounds__(256) void sort_scatter1(
    const int* __restrict__ src, const int* __restrict__ dst,
    int* __restrict__ bucket_cursor, int2* __restrict__ tmp)
{
    __shared__ int ls[S1_CH];
    __shared__ int ld[S1_CH];
    __shared__ int cnt[NBUCK];
    const int t = threadIdx.x;
    for (int b = t; b < NBUCK; b += 256) cnt[b] = 0;
    __syncthreads();
    const int e0 = blockIdx.x * S1_CH;
    const int n = min(S1_CH, E_EDGES - e0);
    for (int i = t; i < n; i += 256) {
        int d = dst[e0 + i];
        ls[i] = src[e0 + i];
        ld[i] = d;
        atomicAdd(&cnt[d >> BSHIFT], 1);
    }
    __syncthreads();
    for (int b = t; b < NBUCK; b += 256) {
        int c = cnt[b];
        cnt[b] = c ? atomicAdd(&bucket_cursor[b], c) : 0;
    }
    __syncthreads();
    for (int i = t; i < n; i += 256) {
        int d = ld[i];
        int pos = atomicAdd(&cnt[d >> BSHIFT], 1);
        tmp[pos] = make_int2(ls[i], d);
    }
}

__global__ __launch_bounds__(256) void sort_scatter2(
    const int2* __restrict__ tmp, const int* __restrict__ bucket_start,
    int* __restrict__ psrc, int* __restrict__ offsets)
{
    __shared__ int2 le[S2_CAP];
    __shared__ int cnt[256];
    __shared__ int s[256];
    __shared__ int cur[256];
    const int t = threadIdx.x;
    const int b = blockIdx.x;
    const int bstart = bucket_start[b];
    const int n = bucket_start[b + 1] - bstart;
    cnt[t] = 0;
    __syncthreads();
    for (int i = t; i < n; i += 256) {
        int2 e = tmp[bstart + i];
        if (i < S2_CAP) le[i] = e;
        atomicAdd(&cnt[e.y & 255], 1);
    }
    __syncthreads();
    int v = cnt[t];
    s[t] = v;
    __syncthreads();
    for (int off = 1; off < 256; off <<= 1) {
        int a = (t >= off) ? s[t - off] : 0;
        __syncthreads();
        s[t] += a;
        __syncthreads();
    }
    int excl = s[t] - v;
    int node = (b << BSHIFT) + t;
    if (node < N_NODES) offsets[node] = bstart + excl;
    cur[t] = excl;
    __syncthreads();
    for (int i = t; i < n; i += 256) {
        int2 e = (i < S2_CAP) ? le[i] : tmp[bstart + i];
        int pos = bstart + atomicAdd(&cur[e.y & 255], 1);
        psrc[pos] = e.x;
    }
}

// ============ FUSED segment reduce: ONE NODE PER 16-LANE GROUP ============
constexpr int FU_BLOCKS = 2048;
constexpr int FU_GROUPS = FU_BLOCKS * 16;

__device__ __forceinline__ float edge_w(
    uint2 e, floatx2 q0, floatx2 q1, floatx2 q2, floatx2 q3)
{
    floatx2 dp = q0 * __builtin_amdgcn_cvt_pk_f32_fp8((int)e.x, false);
    dp += q1 * __builtin_amdgcn_cvt_pk_f32_fp8((int)e.x, true);
    dp += q2 * __builtin_amdgcn_cvt_pk_f32_fp8((int)e.y, false);
    dp += q3 * __builtin_amdgcn_cvt_pk_f32_fp8((int)e.y, true);
    float p = dp.x + dp.y;
    p += __shfl_xor(p, 1);
    return __expf(p * 0.25f);
}
__device__ __forceinline__ void edge_acc(
    uint2 e, float wgt, floatx2& a01, floatx2& a23, floatx2& a45, floatx2& a67)
{
    floatx2 wv = {wgt, wgt};
    a01 += wv * __builtin_amdgcn_cvt_pk_f32_fp8((int)e.x, false);
    a23 += wv * __builtin_amdgcn_cvt_pk_f32_fp8((int)e.x, true);
    a45 += wv * __builtin_amdgcn_cvt_pk_f32_fp8((int)e.y, false);
    a67 += wv * __builtin_amdgcn_cvt_pk_f32_fp8((int)e.y, true);
}

__global__ __launch_bounds__(256) void edge_fused(
    const uchar* __restrict__ qe, const uchar* __restrict__ kb, const uchar* __restrict__ vb,
    const int* __restrict__ psrc, const int* __restrict__ offsets,
    ushort* __restrict__ attended, float* __restrict__ block_l)
{
    const int t = threadIdx.x;
    const int sub = t & 15;
    const int gg0 = blockIdx.x * 16 + (t >> 4);

    float lsum = 0.f;

    for (int d = gg0; d < N_NODES; d += FU_GROUPS) {
        const int start = offsets[d];
        const int end   = offsets[d + 1];

        uint2 qw = *(const uint2*)(qe + (size_t)d * 128 + sub * 8);
        floatx2 q0 = __builtin_amdgcn_cvt_pk_f32_fp8((int)qw.x, false);
        floatx2 q1 = __builtin_amdgcn_cvt_pk_f32_fp8((int)qw.x, true);
        floatx2 q2 = __builtin_amdgcn_cvt_pk_f32_fp8((int)qw.y, false);
        floatx2 q3 = __builtin_amdgcn_cvt_pk_f32_fp8((int)qw.y, true);

        floatx2 a01 = {0.f, 0.f}, a23 = {0.f, 0.f}, a45 = {0.f, 0.f}, a67 = {0.f, 0.f};

        for (int i = start; i < end; i += 4) {
            int i1 = min(i + 1, end - 1);
            int i2 = min(i + 2, end - 1);
            int i3 = min(i + 3, end - 1);
            int s0 = psrc[i];
            int s1 = psrc[i1];
            int s2 = psrc[i2];
            int s3 = psrc[i3];
            uint2 k0 = *(const uint2*)(kb + (size_t)s0 * 128 + sub * 8);
            uint2 k1 = *(const uint2*)(kb + (size_t)s1 * 128 + sub * 8);
            uint2 k2 = *(const uint2*)(kb + (size_t)s2 * 128 + sub * 8);
            uint2 k3 = *(const uint2*)(kb + (size_t)s3 * 128 + sub * 8);
            uint2 v0 = *(const uint2*)(vb + (size_t)s0 * 128 + sub * 8);
            uint2 v1 = *(const uint2*)(vb + (size_t)s1 * 128 + sub * 8);
            uint2 v2 = *(const uint2*)(vb + (size_t)s2 * 128 + sub * 8);
            uint2 v3 = *(const uint2*)(vb + (size_t)s3 * 128 + sub * 8);

            float w0 = edge_w(k0, q0, q1, q2, q3);
            float w1 = edge_w(k1, q0, q1, q2, q3);
            float w2 = edge_w(k2, q0, q1, q2, q3);
            float w3 = edge_w(k3, q0, q1, q2, q3);
            if (i + 1 >= end) w1 = 0.f;
            if (i + 2 >= end) w2 = 0.f;
            if (i + 3 >= end) w3 = 0.f;
            lsum += w0 + w1 + w2 + w3;

            edge_acc(v0, w0, a01, a23, a45, a67);
            edge_acc(v1, w1, a01, a23, a45, a67);
            edge_acc(v2, w2, a01, a23, a45, a67);
            edge_acc(v3, w3, a01, a23, a45, a67);
        }

        uint4 o;
        o.x = (uint)f2bf(a01.x) | ((uint)f2bf(a01.y) << 16);
        o.y = (uint)f2bf(a23.x) | ((uint)f2bf(a23.y) << 16);
        o.z = (uint)f2bf(a45.x) | ((uint)f2bf(a45.y) << 16);
        o.w = (uint)f2bf(a67.x) | ((uint)f2bf(a67.y) << 16);
        *(uint4*)(attended + (size_t)d * HCH + sub * 8) = o;
    }

    __shared__ float sl[256];
    sl[t] = lsum;
    __syncthreads();
    if (t < 8) {
        float L = 0.f;
        for (int base = 0; base < 256; base += 16)
            L += sl[base + 2 * t] + sl[base + 2 * t + 1];
        block_l[blockIdx.x * 8 + t] = 0.5f * L;
    }
}

__global__ __launch_bounds__(256) void reduce_l(
    const float* __restrict__ block_l, float* __restrict__ head_invl, int nblk)
{
    const int t = threadIdx.x;
    float l = 0.f;
    for (int i = t; i < nblk * 8; i += 256) l += block_l[i];
    __shared__ float sl[256];
    sl[t] = l;
    __syncthreads();
    if (t < 8) {
        float L = 0.f;
        for (int i = t; i < 256; i += 8) L += sl[i];
        head_invl[t] = 1.0f / L;
    }
}

extern "C" void kernel_launch(void* const* d_in, const int* in_sizes, int n_in,
                              void* d_out, int out_size, void* d_ws, size_t ws_size,
                              hipStream_t stream)
{
    const float* x  = (const float*)d_in[0];
    const int* eidx = (const int*)d_in[1];
    const float* Wq = (const float*)d_in[2];
    const float* bq = (const float*)d_in[3];
    const float* Wk = (const float*)d_in[4];
    const float* bk = (const float*)d_in[5];
    const float* Wv = (const float*)d_in[6];
    const float* bv = (const float*)d_in[7];
    const float* Wo = (const float*)d_in[8];
    const float* bo = (const float*)d_in[9];
    float* out = (float*)d_out;

    char* ws = (char*)d_ws;
    constexpr size_t SZ_F8  = (size_t)N_NODES * HCH;          // 12.8 MB fp8 per buffer
    constexpr size_t SZ_ATT = (size_t)N_NODES * HCH * 2;      // 25.6 MB bf16 attended
    constexpr size_t SZ_PS  = (size_t)E_EDGES * sizeof(int);  // 6.4 MB
    constexpr size_t SZ_TMP = (size_t)E_EDGES * sizeof(int2); // 12.8 MB
    size_t off = 0;
    uchar* qe = (uchar*)(ws + off); off += SZ_F8;
    uchar* kb = (uchar*)(ws + off); off += SZ_F8;
    uchar* vb = (uchar*)(ws + off); off += SZ_F8;
    ushort* attended = (ushort*)(ws + off); off += SZ_ATT;
    int*    psrc     = (int*)(ws + off);    off += SZ_PS;
    int2*   tmp      = (int2*)(ws + off);   off += SZ_TMP;
    int*    offsets  = (int*)(ws + off);    off += ((size_t)N_NODES + 1) * 4 + 8;
    int*    bucket_total  = (int*)(ws + off); off += (NBUCK + 1) * 4;
    int*    bucket_start  = (int*)(ws + off); off += (NBUCK + 1) * 4;
    int*    bucket_cursor = (int*)(ws + off); off += (NBUCK + 1) * 4;
    float*  block_l   = (float*)(ws + off); off += (size_t)FU_BLOCKS * 8 * sizeof(float);
    float*  head_invl = (float*)(ws + off); off += 32;
    ushort* wall = (ushort*)(ws + off); off += (size_t)512 * HCH * 2;
    const int* src = eidx;
    const int* dst = eidx + E_EDGES;

    dim3 blk(256);

    prep_w<<<32, blk, 0, stream>>>(Wq, Wk, Wv, Wo, wall);

    gemm_qkv<<<768, blk, 0, stream>>>(x, wall, bq, bk, bv, qe, kb, vb, N_NODES);

    hipMemsetAsync(bucket_total, 0, (NBUCK + 1) * 4, stream);
    bucket_hist<<<S1_GRID, blk, 0, stream>>>(dst, bucket_total);
    bucket_scan<<<1, 512, 0, stream>>>(bucket_total, bucket_start, bucket_cursor, offsets);
    sort_scatter1<<<S1_GRID, blk, 0, stream>>>(src, dst, bucket_cursor, tmp);
    sort_scatter2<<<NBUCK, blk, 0, stream>>>(tmp, bucket_start, psrc, offsets);

    edge_fused<<<FU_BLOCKS, blk, 0, stream>>>(qe, kb, vb, psrc, offsets, attended, block_l);
    reduce_l<<<1, blk, 0, stream>>>(block_l, head_invl, FU_BLOCKS);

    gemm_out<<<768, blk, 0, stream>>>(attended, wall, bo, x, head_invl, out, N_NODES);
}

// Round 7
// 295.876 us; speedup vs baseline: 1.3892x; 1.1335x over previous
//
#include <hip/hip_runtime.h>
#include <cstdint>
#include <cstddef>

#define N_NODES 100000
#define E_EDGES 1600000
#define HCH 128
#define NHEADS 8
#define HDIM 16

typedef unsigned int uint;
typedef unsigned short ushort;
typedef unsigned char uchar;
typedef __attribute__((ext_vector_type(8))) short short8;
typedef __attribute__((ext_vector_type(4))) float floatx4;
typedef __attribute__((ext_vector_type(2))) float floatx2;

constexpr int GTILES = (N_NODES + 63) / 64;   // 1563

__device__ __forceinline__ ushort f2bf(float f) {
    uint u = __float_as_uint(f);
    u = (u + 0x7fff + ((u >> 16) & 1)) >> 16;
    return (ushort)u;
}
__device__ __forceinline__ float bflo(uint p) { return __uint_as_float(p << 16); }
__device__ __forceinline__ float bfhi(uint p) { return __uint_as_float(p & 0xffff0000u); }

// ================= sort constants =================
constexpr int BSHIFT = 8;
constexpr int NBUCK  = ((N_NODES - 1) >> BSHIFT) + 1;   // 391
constexpr int S1_GRID = 256;
constexpr int S1_CH   = (E_EDGES + S1_GRID - 1) / S1_GRID;  // 6250
constexpr int S2_CAP  = 6144;
constexpr int FU_BLOCKS = 2048;
constexpr int FU_GROUPS = FU_BLOCKS * 16;

// ============ prep_w: fp32 [K][N] -> bf16 [N][K]; rows 0-127 Wq, 128-255 Wk,
// 256-383 Wv, 384-511 Wo. Block 0 also zeroes bucket_total. ============
__global__ __launch_bounds__(256) void prep_w(
    const float* __restrict__ Wq, const float* __restrict__ Wk,
    const float* __restrict__ Wv, const float* __restrict__ Wo,
    ushort* __restrict__ wall, int* __restrict__ bucket_total)
{
    const int t = threadIdx.x;
    if (blockIdx.x == 0) {
        for (int b = t; b < NBUCK + 1; b += 256) bucket_total[b] = 0;
    }
    int r = blockIdx.x * 16 + (t >> 4);   // 0..511
    int k0 = (t & 15) * 8;
    const float* W;
    if (r < 128)      W = Wq;
    else if (r < 256) W = Wk;
    else if (r < 384) W = Wv;
    else              W = Wo;
    int n = r & 127;
    uint4 u;
    u.x = (uint)f2bf(W[(size_t)(k0 + 0) * HCH + n]) | ((uint)f2bf(W[(size_t)(k0 + 1) * HCH + n]) << 16);
    u.y = (uint)f2bf(W[(size_t)(k0 + 2) * HCH + n]) | ((uint)f2bf(W[(size_t)(k0 + 3) * HCH + n]) << 16);
    u.z = (uint)f2bf(W[(size_t)(k0 + 4) * HCH + n]) | ((uint)f2bf(W[(size_t)(k0 + 5) * HCH + n]) << 16);
    u.w = (uint)f2bf(W[(size_t)(k0 + 6) * HCH + n]) | ((uint)f2bf(W[(size_t)(k0 + 7) * HCH + n]) << 16);
    *(uint4*)(wall + (size_t)r * HCH + k0) = u;
}

__global__ __launch_bounds__(256) void bucket_hist(
    const int* __restrict__ dst, int* __restrict__ bucket_total)
{
    __shared__ int cnt[NBUCK];
    const int t = threadIdx.x;
    for (int b = t; b < NBUCK; b += 256) cnt[b] = 0;
    __syncthreads();
    const int e0 = blockIdx.x * S1_CH;
    const int n = min(S1_CH, E_EDGES - e0);
    for (int i = t; i < n; i += 256)
        atomicAdd(&cnt[dst[e0 + i] >> BSHIFT], 1);
    __syncthreads();
    for (int b = t; b < NBUCK; b += 256)
        if (cnt[b]) atomicAdd(&bucket_total[b], cnt[b]);
}

__global__ __launch_bounds__(512) void bucket_scan(
    const int* __restrict__ bucket_total, int* __restrict__ bucket_start,
    int* __restrict__ bucket_cursor, int* __restrict__ offsets)
{
    __shared__ int s[512];
    const int t = threadIdx.x;
    int v = (t < NBUCK) ? bucket_total[t] : 0;
    s[t] = v;
    __syncthreads();
    for (int off = 1; off < 512; off <<= 1) {
        int a = (t >= off) ? s[t - off] : 0;
        __syncthreads();
        s[t] += a;
        __syncthreads();
    }
    int excl = s[t] - v;
    if (t < NBUCK) { bucket_start[t] = excl; bucket_cursor[t] = excl; }
    if (t == 0) { bucket_start[NBUCK] = E_EDGES; offsets[N_NODES] = E_EDGES; }
}

// ============ MEGA: blocks 0..255 = sort_scatter1; 256..1023 = gemm_qkv ============
// scatter1: two-pass over its edge chunk (no LDS edge cache; L2 re-read), packed tmp.
// gemm_qkv: persistent weight-stationary, T14 reg-prefetch of next A tile, bias hoisted.
__global__ __launch_bounds__(256) void mega_qkv_scatter(
    const float* __restrict__ A, const ushort* __restrict__ wall,
    const float* __restrict__ bq, const float* __restrict__ bk, const float* __restrict__ bv,
    uchar* __restrict__ qe, uchar* __restrict__ kb, uchar* __restrict__ vb,
    const int* __restrict__ src, const int* __restrict__ dst,
    int* __restrict__ bucket_cursor, uint* __restrict__ tmp,
    int M)
{
    __shared__ __align__(16) char sm[34816 + 17408];
    const int t = threadIdx.x;
    const int bid = blockIdx.x;

    if (bid < S1_GRID) {
        // ---------------- sort_scatter1 ----------------
        int* cnt = (int*)sm;
        for (int b = t; b < NBUCK; b += 256) cnt[b] = 0;
        __syncthreads();
        const int e0 = bid * S1_CH;
        const int n = min(S1_CH, E_EDGES - e0);
        for (int i = t; i < n; i += 256)
            atomicAdd(&cnt[dst[e0 + i] >> BSHIFT], 1);
        __syncthreads();
        for (int b = t; b < NBUCK; b += 256) {
            int c = cnt[b];
            cnt[b] = c ? atomicAdd(&bucket_cursor[b], c) : 0;
        }
        __syncthreads();
        for (int i = t; i < n; i += 256) {
            int d = dst[e0 + i];
            int s = src[e0 + i];
            int pos = atomicAdd(&cnt[d >> BSHIFT], 1);
            tmp[pos] = (uint)s | ((uint)(d & 255) << 24);
        }
        return;
    }

    // ---------------- gemm_qkv ----------------
    ushort (*Wt)[136] = (ushort(*)[136])sm;
    ushort (*As)[136] = (ushort(*)[136])(sm + 34816);
    ushort (*Cs)[136] = (ushort(*)[136])(sm + 34816);   // aliased

    const int b = bid - S1_GRID;
    const int mode = b % 3;
    const int tile0 = b / 3;
    const float* bias;
    uchar* outp;
    if (mode == 0)      { bias = bq; outp = qe; }
    else if (mode == 1) { bias = bk; outp = kb; }
    else                { bias = bv; outp = vb; }

#pragma unroll
    for (int i = 0; i < 8; i++) {
        int p = t + i * 256;
        int row = p >> 4, k0 = (p & 15) * 8;
        *(uint4*)(&Wt[row][k0]) =
            *(const uint4*)(wall + ((size_t)(mode * 128 + row)) * HCH + k0);
    }

    const int lane = t & 63;
    const int w = t >> 6;
    const int m_l = lane & 15;
    const int q_l = lane >> 4;

    // bias hoist: epilogue column block is thread-invariant (u = t & 15)
    const int eu = t & 15;
    const float4 eb0 = *(const float4*)(bias + eu * 8);
    const float4 eb1 = *(const float4*)(bias + eu * 8 + 4);
    const int arow = t >> 5, ac4 = t & 31;   // A-stage coords (i-invariant parts)

    // prologue: load tile0 A into regs
    float4 a4[8];
    {
        const int mb = tile0 * 64;
#pragma unroll
        for (int i = 0; i < 8; i++) {
            int row = arow + i * 8;
            int g = mb + row;
            a4[i] = make_float4(0.f, 0.f, 0.f, 0.f);
            if (g < M) a4[i] = *(const float4*)(A + (size_t)g * HCH + ac4 * 4);
        }
    }

    for (int tile = tile0; tile < GTILES; tile += 256) {
        const int mb = tile * 64;
        // write As from staged regs
#pragma unroll
        for (int i = 0; i < 8; i++) {
            uint lo = (uint)f2bf(a4[i].x) | ((uint)f2bf(a4[i].y) << 16);
            uint hi = (uint)f2bf(a4[i].z) | ((uint)f2bf(a4[i].w) << 16);
            *(uint2*)(&As[arow + i * 8][ac4 * 4]) = make_uint2(lo, hi);
        }
        // prefetch next tile (issue-early)
        const int ntile = tile + 256;
        if (ntile < GTILES) {
            const int nmb = ntile * 64;
#pragma unroll
            for (int i = 0; i < 8; i++) {
                int g = nmb + arow + i * 8;
                float4 v = make_float4(0.f, 0.f, 0.f, 0.f);
                if (g < M) v = *(const float4*)(A + (size_t)g * HCH + ac4 * 4);
                a4[i] = v;
            }
        }
        __syncthreads();

        floatx4 acc[8];
#pragma unroll
        for (int tl = 0; tl < 8; tl++) acc[tl] = (floatx4){0.f, 0.f, 0.f, 0.f};
#pragma unroll
        for (int ks = 0; ks < 4; ks++) {
            short8 af = *(const short8*)(&As[w * 16 + m_l][ks * 32 + q_l * 8]);
#pragma unroll
            for (int tl = 0; tl < 8; tl++) {
                short8 bf = *(const short8*)(&Wt[tl * 16 + m_l][ks * 32 + q_l * 8]);
                acc[tl] = __builtin_amdgcn_mfma_f32_16x16x32_bf16(af, bf, acc[tl], 0, 0, 0);
            }
        }
        __syncthreads();

#pragma unroll
        for (int tl = 0; tl < 8; tl++)
#pragma unroll
            for (int r = 0; r < 4; r++)
                Cs[w * 16 + q_l * 4 + r][tl * 16 + m_l] = f2bf(acc[tl][r]);
        __syncthreads();

        // epilogue: full 128B fp8 rows
#pragma unroll
        for (int i = 0; i < 4; i++) {
            int row = (t >> 4) + i * 16;
            int g = mb + row;
            if (g < M) {
                uint4 c = *(const uint4*)(&Cs[row][eu * 8]);
                int r0 = __builtin_amdgcn_cvt_pk_fp8_f32(bflo(c.x) + eb0.x, bfhi(c.x) + eb0.y, 0, false);
                r0 = __builtin_amdgcn_cvt_pk_fp8_f32(bflo(c.y) + eb0.z, bfhi(c.y) + eb0.w, r0, true);
                int r1 = __builtin_amdgcn_cvt_pk_fp8_f32(bflo(c.z) + eb1.x, bfhi(c.z) + eb1.y, 0, false);
                r1 = __builtin_amdgcn_cvt_pk_fp8_f32(bflo(c.w) + eb1.z, bfhi(c.w) + eb1.w, r1, true);
                *(uint2*)(outp + (size_t)g * 128 + eu * 8) = make_uint2((uint)r0, (uint)r1);
            }
        }
        __syncthreads();
    }
}

__global__ __launch_bounds__(256) void sort_scatter2(
    const uint* __restrict__ tmp, const int* __restrict__ bucket_start,
    int* __restrict__ psrc, int* __restrict__ offsets)
{
    __shared__ uint le[S2_CAP];
    __shared__ int cnt[256];
    __shared__ int s[256];
    __shared__ int cur[256];
    const int t = threadIdx.x;
    const int b = blockIdx.x;
    const int bstart = bucket_start[b];
    const int n = bucket_start[b + 1] - bstart;
    cnt[t] = 0;
    __syncthreads();
    for (int i = t; i < n; i += 256) {
        uint e = tmp[bstart + i];
        if (i < S2_CAP) le[i] = e;
        atomicAdd(&cnt[e >> 24], 1);
    }
    __syncthreads();
    int v = cnt[t];
    s[t] = v;
    __syncthreads();
    for (int off = 1; off < 256; off <<= 1) {
        int a = (t >= off) ? s[t - off] : 0;
        __syncthreads();
        s[t] += a;
        __syncthreads();
    }
    int excl = s[t] - v;
    int node = (b << BSHIFT) + t;
    if (node < N_NODES) offsets[node] = bstart + excl;
    cur[t] = excl;
    __syncthreads();
    for (int i = t; i < n; i += 256) {
        uint e = (i < S2_CAP) ? le[i] : tmp[bstart + i];
        int pos = bstart + atomicAdd(&cur[e >> 24], 1);
        psrc[pos] = (int)(e & 0x1FFFFu);
    }
}

// ============ FUSED segment reduce: one node per 16-lane group, 2-batch SWP ============
__device__ __forceinline__ float edge_w(
    uint2 e, floatx2 q0, floatx2 q1, floatx2 q2, floatx2 q3)
{
    floatx2 dp = q0 * __builtin_amdgcn_cvt_pk_f32_fp8((int)e.x, false);
    dp += q1 * __builtin_amdgcn_cvt_pk_f32_fp8((int)e.x, true);
    dp += q2 * __builtin_amdgcn_cvt_pk_f32_fp8((int)e.y, false);
    dp += q3 * __builtin_amdgcn_cvt_pk_f32_fp8((int)e.y, true);
    float p = dp.x + dp.y;
    p += __shfl_xor(p, 1);
    return __expf(p * 0.25f);
}
__device__ __forceinline__ void edge_acc(
    uint2 e, float wgt, floatx2& a01, floatx2& a23, floatx2& a45, floatx2& a67)
{
    floatx2 wv = {wgt, wgt};
    a01 += wv * __builtin_amdgcn_cvt_pk_f32_fp8((int)e.x, false);
    a23 += wv * __builtin_amdgcn_cvt_pk_f32_fp8((int)e.x, true);
    a45 += wv * __builtin_amdgcn_cvt_pk_f32_fp8((int)e.y, false);
    a67 += wv * __builtin_amdgcn_cvt_pk_f32_fp8((int)e.y, true);
}

#define LOADQ(S, base) do { \
    int jj1 = min((base) + 1, end - 1); \
    int jj2 = min((base) + 2, end - 1); \
    int jj3 = min((base) + 3, end - 1); \
    int u0 = psrc[(base)], u1 = psrc[jj1], u2 = psrc[jj2], u3 = psrc[jj3]; \
    k##S##0 = *(const uint2*)(kb + (size_t)u0 * 128 + sub * 8); \
    k##S##1 = *(const uint2*)(kb + (size_t)u1 * 128 + sub * 8); \
    k##S##2 = *(const uint2*)(kb + (size_t)u2 * 128 + sub * 8); \
    k##S##3 = *(const uint2*)(kb + (size_t)u3 * 128 + sub * 8); \
    v##S##0 = *(const uint2*)(vb + (size_t)u0 * 128 + sub * 8); \
    v##S##1 = *(const uint2*)(vb + (size_t)u1 * 128 + sub * 8); \
    v##S##2 = *(const uint2*)(vb + (size_t)u2 * 128 + sub * 8); \
    v##S##3 = *(const uint2*)(vb + (size_t)u3 * 128 + sub * 8); \
} while (0)

#define COMPQ(S, base) do { \
    float w0 = edge_w(k##S##0, q0, q1, q2, q3); \
    float w1 = edge_w(k##S##1, q0, q1, q2, q3); \
    float w2 = edge_w(k##S##2, q0, q1, q2, q3); \
    float w3 = edge_w(k##S##3, q0, q1, q2, q3); \
    if ((base) + 1 >= end) w1 = 0.f; \
    if ((base) + 2 >= end) w2 = 0.f; \
    if ((base) + 3 >= end) w3 = 0.f; \
    lsum += w0 + w1 + w2 + w3; \
    edge_acc(v##S##0, w0, a01, a23, a45, a67); \
    edge_acc(v##S##1, w1, a01, a23, a45, a67); \
    edge_acc(v##S##2, w2, a01, a23, a45, a67); \
    edge_acc(v##S##3, w3, a01, a23, a45, a67); \
} while (0)

__global__ __launch_bounds__(256) void edge_fused(
    const uchar* __restrict__ qe, const uchar* __restrict__ kb, const uchar* __restrict__ vb,
    const int* __restrict__ psrc, const int* __restrict__ offsets,
    ushort* __restrict__ attended, float* __restrict__ block_l)
{
    const int t = threadIdx.x;
    const int sub = t & 15;
    const int gg0 = blockIdx.x * 16 + (t >> 4);

    float lsum = 0.f;

    for (int d = gg0; d < N_NODES; d += FU_GROUPS) {
        const int start = offsets[d];
        const int end   = offsets[d + 1];

        uint2 qw = *(const uint2*)(qe + (size_t)d * 128 + sub * 8);
        floatx2 q0 = __builtin_amdgcn_cvt_pk_f32_fp8((int)qw.x, false);
        floatx2 q1 = __builtin_amdgcn_cvt_pk_f32_fp8((int)qw.x, true);
        floatx2 q2 = __builtin_amdgcn_cvt_pk_f32_fp8((int)qw.y, false);
        floatx2 q3 = __builtin_amdgcn_cvt_pk_f32_fp8((int)qw.y, true);

        floatx2 a01 = {0.f, 0.f}, a23 = {0.f, 0.f}, a45 = {0.f, 0.f}, a67 = {0.f, 0.f};

        uint2 kA0, kA1, kA2, kA3, vA0, vA1, vA2, vA3;
        uint2 kB0, kB1, kB2, kB3, vB0, vB1, vB2, vB3;

        int i = start;
        if (i < end) {
            LOADQ(A, i);
            while (true) {
                if (i + 4 < end) LOADQ(B, i + 4);
                COMPQ(A, i);
                i += 4;
                if (i >= end) break;
                if (i + 4 < end) LOADQ(A, i + 4);
                COMPQ(B, i);
                i += 4;
                if (i >= end) break;
            }
        }

        uint4 o;
        o.x = (uint)f2bf(a01.x) | ((uint)f2bf(a01.y) << 16);
        o.y = (uint)f2bf(a23.x) | ((uint)f2bf(a23.y) << 16);
        o.z = (uint)f2bf(a45.x) | ((uint)f2bf(a45.y) << 16);
        o.w = (uint)f2bf(a67.x) | ((uint)f2bf(a67.y) << 16);
        *(uint4*)(attended + (size_t)d * HCH + sub * 8) = o;
    }

    __shared__ float sl[256];
    sl[t] = lsum;
    __syncthreads();
    if (t < 8) {
        float L = 0.f;
        for (int base = 0; base < 256; base += 16)
            L += sl[base + 2 * t] + sl[base + 2 * t + 1];
        block_l[blockIdx.x * 8 + t] = 0.5f * L;
    }
}

// ============ gemm_out: persistent; folds the L-reduction (per-block, L2-hot) ============
__global__ __launch_bounds__(256) void gemm_out(
    const ushort* __restrict__ A, const ushort* __restrict__ wall,
    const float* __restrict__ bias, const float* __restrict__ res,
    const float* __restrict__ block_l,
    float* __restrict__ C, int M)
{
    __shared__ __align__(16) char sm[34816 + 17408];
    ushort (*Wt)[136] = (ushort(*)[136])sm;
    ushort (*As)[136] = (ushort(*)[136])(sm + 34816);
    ushort (*Cs)[136] = (ushort(*)[136])(sm + 34816);
    __shared__ float invl_s[8];
    __shared__ float sl[256];

    const int t = threadIdx.x;

    // fold reduce_l: per-block redundant reduction of block_l[FU_BLOCKS*8]
    {
        float l = 0.f;
        for (int i = t; i < FU_BLOCKS * 8; i += 256) l += block_l[i];
        sl[t] = l;   // partial for head t&7
        __syncthreads();
        if (t < 8) {
            float L = 0.f;
            for (int j = t; j < 256; j += 8) L += sl[j];
            invl_s[t] = 1.0f / L;
        }
    }

#pragma unroll
    for (int i = 0; i < 8; i++) {
        int p = t + i * 256;
        int row = p >> 4, k0 = (p & 15) * 8;
        *(uint4*)(&Wt[row][k0]) =
            *(const uint4*)(wall + ((size_t)(384 + row)) * HCH + k0);
    }
    __syncthreads();

    const int lane = t & 63;
    const int w = t >> 6;
    const int m_l = lane & 15;
    const int q_l = lane >> 4;

    const int arow = t >> 5, acu2 = t & 31;
    const float invl_a = invl_s[acu2 >> 2];
    const int eu = t & 31;
    const float4 eb = *(const float4*)(bias + eu * 4);

    // prologue A load
    uint2 a2[8];
    {
        const int mb = blockIdx.x * 64;
#pragma unroll
        for (int i = 0; i < 8; i++) {
            int g = mb + arow + i * 8;
            a2[i] = make_uint2(0, 0);
            if (g < M) a2[i] = *(const uint2*)(A + (size_t)g * HCH + acu2 * 4);
        }
    }

    for (int tile = blockIdx.x; tile < GTILES; tile += 768) {
        const int mb = tile * 64;
#pragma unroll
        for (int i = 0; i < 8; i++) {
            float f0 = bflo(a2[i].x) * invl_a, f1 = bfhi(a2[i].x) * invl_a;
            float f2 = bflo(a2[i].y) * invl_a, f3 = bfhi(a2[i].y) * invl_a;
            uint lo = (uint)f2bf(f0) | ((uint)f2bf(f1) << 16);
            uint hi = (uint)f2bf(f2) | ((uint)f2bf(f3) << 16);
            *(uint2*)(&As[arow + i * 8][acu2 * 4]) = make_uint2(lo, hi);
        }
        const int ntile = tile + 768;
        if (ntile < GTILES) {
            const int nmb = ntile * 64;
#pragma unroll
            for (int i = 0; i < 8; i++) {
                int g = nmb + arow + i * 8;
                uint2 v = make_uint2(0, 0);
                if (g < M) v = *(const uint2*)(A + (size_t)g * HCH + acu2 * 4);
                a2[i] = v;
            }
        }
        __syncthreads();

        floatx4 acc[8];
#pragma unroll
        for (int tl = 0; tl < 8; tl++) acc[tl] = (floatx4){0.f, 0.f, 0.f, 0.f};
#pragma unroll
        for (int ks = 0; ks < 4; ks++) {
            short8 af = *(const short8*)(&As[w * 16 + m_l][ks * 32 + q_l * 8]);
#pragma unroll
            for (int tl = 0; tl < 8; tl++) {
                short8 bf = *(const short8*)(&Wt[tl * 16 + m_l][ks * 32 + q_l * 8]);
                acc[tl] = __builtin_amdgcn_mfma_f32_16x16x32_bf16(af, bf, acc[tl], 0, 0, 0);
            }
        }
        __syncthreads();

#pragma unroll
        for (int tl = 0; tl < 8; tl++)
#pragma unroll
            for (int r = 0; r < 4; r++)
                Cs[w * 16 + q_l * 4 + r][tl * 16 + m_l] = f2bf(acc[tl][r]);
        __syncthreads();

#pragma unroll
        for (int i = 0; i < 8; i++) {
            int row = (t >> 5) + i * 8;
            int g = mb + row;
            if (g < M) {
                uint2 c = *(const uint2*)(&Cs[row][eu * 4]);
                float4 r4 = *(const float4*)(res + (size_t)g * HCH + eu * 4);
                float4 o;
                o.x = bflo(c.x) + eb.x + r4.x;
                o.y = bfhi(c.x) + eb.y + r4.y;
                o.z = bflo(c.y) + eb.z + r4.z;
                o.w = bfhi(c.y) + eb.w + r4.w;
                *(float4*)(C + (size_t)g * HCH + eu * 4) = o;
            }
        }
        __syncthreads();
    }
}

extern "C" void kernel_launch(void* const* d_in, const int* in_sizes, int n_in,
                              void* d_out, int out_size, void* d_ws, size_t ws_size,
                              hipStream_t stream)
{
    const float* x  = (const float*)d_in[0];
    const int* eidx = (const int*)d_in[1];
    const float* Wq = (const float*)d_in[2];
    const float* bq = (const float*)d_in[3];
    const float* Wk = (const float*)d_in[4];
    const float* bk = (const float*)d_in[5];
    const float* Wv = (const float*)d_in[6];
    const float* bv = (const float*)d_in[7];
    const float* Wo = (const float*)d_in[8];
    const float* bo = (const float*)d_in[9];
    float* out = (float*)d_out;

    char* ws = (char*)d_ws;
    constexpr size_t SZ_F8  = (size_t)N_NODES * HCH;          // 12.8 MB fp8 per buffer
    constexpr size_t SZ_ATT = (size_t)N_NODES * HCH * 2;      // 25.6 MB bf16 attended
    constexpr size_t SZ_PS  = (size_t)E_EDGES * sizeof(int);  // 6.4 MB
    constexpr size_t SZ_TMP = (size_t)E_EDGES * sizeof(uint); // 6.4 MB packed
    size_t off = 0;
    uchar* qe = (uchar*)(ws + off); off += SZ_F8;
    uchar* kb = (uchar*)(ws + off); off += SZ_F8;
    uchar* vb = (uchar*)(ws + off); off += SZ_F8;
    ushort* attended = (ushort*)(ws + off); off += SZ_ATT;
    int*    psrc     = (int*)(ws + off);    off += SZ_PS;
    uint*   tmp      = (uint*)(ws + off);   off += SZ_TMP;
    int*    offsets  = (int*)(ws + off);    off += ((size_t)N_NODES + 1) * 4 + 8;
    int*    bucket_total  = (int*)(ws + off); off += (NBUCK + 1) * 4;
    int*    bucket_start  = (int*)(ws + off); off += (NBUCK + 1) * 4;
    int*    bucket_cursor = (int*)(ws + off); off += (NBUCK + 1) * 4;
    float*  block_l   = (float*)(ws + off); off += (size_t)FU_BLOCKS * 8 * sizeof(float);
    ushort* wall = (ushort*)(ws + off); off += (size_t)512 * HCH * 2;
    const int* src = eidx;
    const int* dst = eidx + E_EDGES;

    dim3 blk(256);

    prep_w<<<32, blk, 0, stream>>>(Wq, Wk, Wv, Wo, wall, bucket_total);
    bucket_hist<<<S1_GRID, blk, 0, stream>>>(dst, bucket_total);
    bucket_scan<<<1, 512, 0, stream>>>(bucket_total, bucket_start, bucket_cursor, offsets);

    mega_qkv_scatter<<<S1_GRID + 768, blk, 0, stream>>>(
        x, wall, bq, bk, bv, qe, kb, vb, src, dst, bucket_cursor, tmp, N_NODES);

    sort_scatter2<<<NBUCK, blk, 0, stream>>>(tmp, bucket_start, psrc, offsets);

    edge_fused<<<FU_BLOCKS, blk, 0, stream>>>(qe, kb, vb, psrc, offsets, attended, block_l);

    gemm_out<<<768, blk, 0, stream>>>(attended, wall, bo, x, block_l, out, N_NODES);
}

// Round 8
// 292.747 us; speedup vs baseline: 1.4040x; 1.0107x over previous
//
#include <hip/hip_runtime.h>
#include <cstdint>
#include <cstddef>

#define N_NODES 100000
#define E_EDGES 1600000
#define HCH 128
#define NHEADS 8
#define HDIM 16

typedef unsigned int uint;
typedef unsigned short ushort;
typedef unsigned char uchar;
typedef __attribute__((ext_vector_type(8))) short short8;
typedef __attribute__((ext_vector_type(4))) float floatx4;
typedef __attribute__((ext_vector_type(2))) float floatx2;

constexpr int GTILES = (N_NODES + 63) / 64;   // 1563

__device__ __forceinline__ ushort f2bf(float f) {
    uint u = __float_as_uint(f);
    u = (u + 0x7fff + ((u >> 16) & 1)) >> 16;
    return (ushort)u;
}
__device__ __forceinline__ float bflo(uint p) { return __uint_as_float(p << 16); }
__device__ __forceinline__ float bfhi(uint p) { return __uint_as_float(p & 0xffff0000u); }

// ================= sort constants =================
constexpr int BSHIFT = 8;
constexpr int NBUCK  = ((N_NODES - 1) >> BSHIFT) + 1;   // 391
constexpr int S1_GRID = 256;
constexpr int S1_CH   = (E_EDGES + S1_GRID - 1) / S1_GRID;  // 6250
constexpr int S2_CAP  = 6144;
constexpr int FU_BLOCKS = 2048;
constexpr int FU_GROUPS = FU_BLOCKS * 16;
constexpr int GQ_BLOCKS = 1278;     // 426 per qkv mode
constexpr int GQ_STRIDE = 426;
constexpr int GO_BLOCKS = 1024;

// ============ prep_hist: blocks 0-255 = bucket_hist; 256-287 = prep_w ============
// wall rows: 0-127 Wq, 128-255 Wk, 256-383 Wv, 384-511 Wo; bf16 [N][K].
// bucket_total must be pre-zeroed (hipMemsetAsync).
__global__ __launch_bounds__(256) void prep_hist(
    const float* __restrict__ Wq, const float* __restrict__ Wk,
    const float* __restrict__ Wv, const float* __restrict__ Wo,
    ushort* __restrict__ wall,
    const int* __restrict__ dst, int* __restrict__ bucket_total)
{
    const int t = threadIdx.x;
    const int bid = blockIdx.x;
    if (bid < S1_GRID) {
        __shared__ int cnt[NBUCK];
        for (int b = t; b < NBUCK; b += 256) cnt[b] = 0;
        __syncthreads();
        const int e0 = bid * S1_CH;
        const int n = min(S1_CH, E_EDGES - e0);
        for (int i = t; i < n; i += 256)
            atomicAdd(&cnt[dst[e0 + i] >> BSHIFT], 1);
        __syncthreads();
        for (int b = t; b < NBUCK; b += 256)
            if (cnt[b]) atomicAdd(&bucket_total[b], cnt[b]);
        return;
    }
    int r = (bid - S1_GRID) * 16 + (t >> 4);   // 0..511
    int k0 = (t & 15) * 8;
    const float* W;
    if (r < 128)      W = Wq;
    else if (r < 256) W = Wk;
    else if (r < 384) W = Wv;
    else              W = Wo;
    int n = r & 127;
    uint4 u;
    u.x = (uint)f2bf(W[(size_t)(k0 + 0) * HCH + n]) | ((uint)f2bf(W[(size_t)(k0 + 1) * HCH + n]) << 16);
    u.y = (uint)f2bf(W[(size_t)(k0 + 2) * HCH + n]) | ((uint)f2bf(W[(size_t)(k0 + 3) * HCH + n]) << 16);
    u.z = (uint)f2bf(W[(size_t)(k0 + 4) * HCH + n]) | ((uint)f2bf(W[(size_t)(k0 + 5) * HCH + n]) << 16);
    u.w = (uint)f2bf(W[(size_t)(k0 + 6) * HCH + n]) | ((uint)f2bf(W[(size_t)(k0 + 7) * HCH + n]) << 16);
    *(uint4*)(wall + (size_t)r * HCH + k0) = u;
}

__global__ __launch_bounds__(512) void bucket_scan(
    const int* __restrict__ bucket_total, int* __restrict__ bucket_start,
    int* __restrict__ bucket_cursor, int* __restrict__ offsets)
{
    __shared__ int s[512];
    const int t = threadIdx.x;
    int v = (t < NBUCK) ? bucket_total[t] : 0;
    s[t] = v;
    __syncthreads();
    for (int off = 1; off < 512; off <<= 1) {
        int a = (t >= off) ? s[t - off] : 0;
        __syncthreads();
        s[t] += a;
        __syncthreads();
    }
    int excl = s[t] - v;
    if (t < NBUCK) { bucket_start[t] = excl; bucket_cursor[t] = excl; }
    if (t == 0) { bucket_start[NBUCK] = E_EDGES; offsets[N_NODES] = E_EDGES; }
}

// ============ MEGA: blocks 0..255 = sort_scatter1; 256.. = gemm_qkv (W in regs) ============
__global__ __launch_bounds__(256) void mega_qkv_scatter(
    const float* __restrict__ A, const ushort* __restrict__ wall,
    const float* __restrict__ bq, const float* __restrict__ bk, const float* __restrict__ bv,
    uchar* __restrict__ qe, uchar* __restrict__ kb, uchar* __restrict__ vb,
    const int* __restrict__ src, const int* __restrict__ dst,
    int* __restrict__ bucket_cursor, uint* __restrict__ tmp,
    int M)
{
    __shared__ __align__(16) char sm[34816];
    const int t = threadIdx.x;
    const int bid = blockIdx.x;

    if (bid < S1_GRID) {
        // ---------------- sort_scatter1 ----------------
        int* cnt = (int*)sm;
        for (int b = t; b < NBUCK; b += 256) cnt[b] = 0;
        __syncthreads();
        const int e0 = bid * S1_CH;
        const int n = min(S1_CH, E_EDGES - e0);
        for (int i = t; i < n; i += 256)
            atomicAdd(&cnt[dst[e0 + i] >> BSHIFT], 1);
        __syncthreads();
        for (int b = t; b < NBUCK; b += 256) {
            int c = cnt[b];
            cnt[b] = c ? atomicAdd(&bucket_cursor[b], c) : 0;
        }
        __syncthreads();
        for (int i = t; i < n; i += 256) {
            int d = dst[e0 + i];
            int s = src[e0 + i];
            int pos = atomicAdd(&cnt[d >> BSHIFT], 1);
            tmp[pos] = (uint)s | ((uint)(d & 255) << 24);
        }
        return;
    }

    // ---------------- gemm_qkv: W fragments in registers ----------------
    ushort (*As)[136] = (ushort(*)[136])sm;
    ushort (*Cs)[136] = (ushort(*)[136])(sm + 17408);

    const int b = bid - S1_GRID;
    const int mode = b % 3;
    const int tile0 = b / 3;
    const float* bias;
    uchar* outp;
    if (mode == 0)      { bias = bq; outp = qe; }
    else if (mode == 1) { bias = bk; outp = kb; }
    else                { bias = bv; outp = vb; }

    const int lane = t & 63;
    const int w = t >> 6;
    const int m_l = lane & 15;
    const int q_l = lane >> 4;

    // each wave owns col-tiles {2w, 2w+1}: 8 B-fragments in 32 VGPRs
    short8 wfr[2][4];
    {
        const ushort* wb = wall + (size_t)(mode * 128 + 2 * w * 16 + m_l) * HCH + q_l * 8;
#pragma unroll
        for (int tlj = 0; tlj < 2; tlj++)
#pragma unroll
            for (int ks = 0; ks < 4; ks++)
                wfr[tlj][ks] = *(const short8*)(wb + (size_t)tlj * 16 * HCH + ks * 32);
    }

    const int eu = t & 15;
    const float4 eb0 = *(const float4*)(bias + eu * 8);
    const float4 eb1 = *(const float4*)(bias + eu * 8 + 4);
    const int arow = t >> 5, ac4 = t & 31;

    // prologue A load
    float4 a4[8];
    {
        const int mb = tile0 * 64;
#pragma unroll
        for (int i = 0; i < 8; i++) {
            int g = mb + arow + i * 8;
            a4[i] = make_float4(0.f, 0.f, 0.f, 0.f);
            if (g < M) a4[i] = *(const float4*)(A + (size_t)g * HCH + ac4 * 4);
        }
    }

    for (int tile = tile0; tile < GTILES; tile += GQ_STRIDE) {
        const int mb = tile * 64;
#pragma unroll
        for (int i = 0; i < 8; i++) {
            uint lo = (uint)f2bf(a4[i].x) | ((uint)f2bf(a4[i].y) << 16);
            uint hi = (uint)f2bf(a4[i].z) | ((uint)f2bf(a4[i].w) << 16);
            *(uint2*)(&As[arow + i * 8][ac4 * 4]) = make_uint2(lo, hi);
        }
        const int ntile = tile + GQ_STRIDE;
        if (ntile < GTILES) {
            const int nmb = ntile * 64;
#pragma unroll
            for (int i = 0; i < 8; i++) {
                int g = nmb + arow + i * 8;
                float4 v = make_float4(0.f, 0.f, 0.f, 0.f);
                if (g < M) v = *(const float4*)(A + (size_t)g * HCH + ac4 * 4);
                a4[i] = v;
            }
        }
        __syncthreads();

        floatx4 acc[4][2];
#pragma unroll
        for (int ms = 0; ms < 4; ms++) {
            acc[ms][0] = (floatx4){0.f, 0.f, 0.f, 0.f};
            acc[ms][1] = (floatx4){0.f, 0.f, 0.f, 0.f};
        }
#pragma unroll
        for (int ks = 0; ks < 4; ks++) {
#pragma unroll
            for (int ms = 0; ms < 4; ms++) {
                short8 af = *(const short8*)(&As[ms * 16 + m_l][ks * 32 + q_l * 8]);
                acc[ms][0] = __builtin_amdgcn_mfma_f32_16x16x32_bf16(af, wfr[0][ks], acc[ms][0], 0, 0, 0);
                acc[ms][1] = __builtin_amdgcn_mfma_f32_16x16x32_bf16(af, wfr[1][ks], acc[ms][1], 0, 0, 0);
            }
        }
#pragma unroll
        for (int ms = 0; ms < 4; ms++)
#pragma unroll
            for (int tlj = 0; tlj < 2; tlj++)
#pragma unroll
                for (int r = 0; r < 4; r++)
                    Cs[ms * 16 + q_l * 4 + r][(2 * w + tlj) * 16 + m_l] = f2bf(acc[ms][tlj][r]);
        __syncthreads();

#pragma unroll
        for (int i = 0; i < 4; i++) {
            int row = (t >> 4) + i * 16;
            int g = mb + row;
            if (g < M) {
                uint4 c = *(const uint4*)(&Cs[row][eu * 8]);
                int r0 = __builtin_amdgcn_cvt_pk_fp8_f32(bflo(c.x) + eb0.x, bfhi(c.x) + eb0.y, 0, false);
                r0 = __builtin_amdgcn_cvt_pk_fp8_f32(bflo(c.y) + eb0.z, bfhi(c.y) + eb0.w, r0, true);
                int r1 = __builtin_amdgcn_cvt_pk_fp8_f32(bflo(c.z) + eb1.x, bfhi(c.z) + eb1.y, 0, false);
                r1 = __builtin_amdgcn_cvt_pk_fp8_f32(bflo(c.w) + eb1.z, bfhi(c.w) + eb1.w, r1, true);
                *(uint2*)(outp + (size_t)g * 128 + eu * 8) = make_uint2((uint)r0, (uint)r1);
            }
        }
        __syncthreads();
    }
}

__global__ __launch_bounds__(256) void sort_scatter2(
    const uint* __restrict__ tmp, const int* __restrict__ bucket_start,
    int* __restrict__ psrc, int* __restrict__ offsets)
{
    __shared__ uint le[S2_CAP];
    __shared__ int cnt[256];
    __shared__ int s[256];
    __shared__ int cur[256];
    const int t = threadIdx.x;
    const int b = blockIdx.x;
    const int bstart = bucket_start[b];
    const int n = bucket_start[b + 1] - bstart;
    cnt[t] = 0;
    __syncthreads();
    for (int i = t; i < n; i += 256) {
        uint e = tmp[bstart + i];
        if (i < S2_CAP) le[i] = e;
        atomicAdd(&cnt[e >> 24], 1);
    }
    __syncthreads();
    int v = cnt[t];
    s[t] = v;
    __syncthreads();
    for (int off = 1; off < 256; off <<= 1) {
        int a = (t >= off) ? s[t - off] : 0;
        __syncthreads();
        s[t] += a;
        __syncthreads();
    }
    int excl = s[t] - v;
    int node = (b << BSHIFT) + t;
    if (node < N_NODES) offsets[node] = bstart + excl;
    cur[t] = excl;
    __syncthreads();
    for (int i = t; i < n; i += 256) {
        uint e = (i < S2_CAP) ? le[i] : tmp[bstart + i];
        int pos = bstart + atomicAdd(&cur[e >> 24], 1);
        psrc[pos] = (int)(e & 0x1FFFFu);
    }
}

// ============ FUSED segment reduce: one node per 16-lane group, 2-batch SWP ============
// w folded by 1/16 (exp bias -ln16) so fp8 attended has range headroom; L scales
// identically so normalization is exact.
__device__ __forceinline__ float edge_w(
    uint2 e, floatx2 q0, floatx2 q1, floatx2 q2, floatx2 q3)
{
    floatx2 dp = q0 * __builtin_amdgcn_cvt_pk_f32_fp8((int)e.x, false);
    dp += q1 * __builtin_amdgcn_cvt_pk_f32_fp8((int)e.x, true);
    dp += q2 * __builtin_amdgcn_cvt_pk_f32_fp8((int)e.y, false);
    dp += q3 * __builtin_amdgcn_cvt_pk_f32_fp8((int)e.y, true);
    float p = dp.x + dp.y;
    p += __shfl_xor(p, 1);
    return __expf(p * 0.25f - 2.772588722f);   // exp(s)/16
}
__device__ __forceinline__ void edge_acc(
    uint2 e, float wgt, floatx2& a01, floatx2& a23, floatx2& a45, floatx2& a67)
{
    floatx2 wv = {wgt, wgt};
    a01 += wv * __builtin_amdgcn_cvt_pk_f32_fp8((int)e.x, false);
    a23 += wv * __builtin_amdgcn_cvt_pk_f32_fp8((int)e.x, true);
    a45 += wv * __builtin_amdgcn_cvt_pk_f32_fp8((int)e.y, false);
    a67 += wv * __builtin_amdgcn_cvt_pk_f32_fp8((int)e.y, true);
}

#define LOADQ(S, base) do { \
    int jj1 = min((base) + 1, end - 1); \
    int jj2 = min((base) + 2, end - 1); \
    int jj3 = min((base) + 3, end - 1); \
    int u0 = psrc[(base)], u1 = psrc[jj1], u2 = psrc[jj2], u3 = psrc[jj3]; \
    k##S##0 = *(const uint2*)(kb + (size_t)u0 * 128 + sub * 8); \
    k##S##1 = *(const uint2*)(kb + (size_t)u1 * 128 + sub * 8); \
    k##S##2 = *(const uint2*)(kb + (size_t)u2 * 128 + sub * 8); \
    k##S##3 = *(const uint2*)(kb + (size_t)u3 * 128 + sub * 8); \
    v##S##0 = *(const uint2*)(vb + (size_t)u0 * 128 + sub * 8); \
    v##S##1 = *(const uint2*)(vb + (size_t)u1 * 128 + sub * 8); \
    v##S##2 = *(const uint2*)(vb + (size_t)u2 * 128 + sub * 8); \
    v##S##3 = *(const uint2*)(vb + (size_t)u3 * 128 + sub * 8); \
} while (0)

#define COMPQ(S, base) do { \
    float w0 = edge_w(k##S##0, q0, q1, q2, q3); \
    float w1 = edge_w(k##S##1, q0, q1, q2, q3); \
    float w2 = edge_w(k##S##2, q0, q1, q2, q3); \
    float w3 = edge_w(k##S##3, q0, q1, q2, q3); \
    if ((base) + 1 >= end) w1 = 0.f; \
    if ((base) + 2 >= end) w2 = 0.f; \
    if ((base) + 3 >= end) w3 = 0.f; \
    lsum += w0 + w1 + w2 + w3; \
    edge_acc(v##S##0, w0, a01, a23, a45, a67); \
    edge_acc(v##S##1, w1, a01, a23, a45, a67); \
    edge_acc(v##S##2, w2, a01, a23, a45, a67); \
    edge_acc(v##S##3, w3, a01, a23, a45, a67); \
} while (0)

__global__ __launch_bounds__(256) void edge_fused(
    const uchar* __restrict__ qe, const uchar* __restrict__ kb, const uchar* __restrict__ vb,
    const int* __restrict__ psrc, const int* __restrict__ offsets,
    uchar* __restrict__ attended, float* __restrict__ block_l)
{
    const int t = threadIdx.x;
    const int sub = t & 15;
    const int gg0 = blockIdx.x * 16 + (t >> 4);

    float lsum = 0.f;

    for (int d = gg0; d < N_NODES; d += FU_GROUPS) {
        const int start = offsets[d];
        const int end   = offsets[d + 1];

        uint2 qw = *(const uint2*)(qe + (size_t)d * 128 + sub * 8);
        floatx2 q0 = __builtin_amdgcn_cvt_pk_f32_fp8((int)qw.x, false);
        floatx2 q1 = __builtin_amdgcn_cvt_pk_f32_fp8((int)qw.x, true);
        floatx2 q2 = __builtin_amdgcn_cvt_pk_f32_fp8((int)qw.y, false);
        floatx2 q3 = __builtin_amdgcn_cvt_pk_f32_fp8((int)qw.y, true);

        floatx2 a01 = {0.f, 0.f}, a23 = {0.f, 0.f}, a45 = {0.f, 0.f}, a67 = {0.f, 0.f};

        uint2 kA0, kA1, kA2, kA3, vA0, vA1, vA2, vA3;
        uint2 kB0, kB1, kB2, kB3, vB0, vB1, vB2, vB3;

        int i = start;
        if (i < end) {
            LOADQ(A, i);
            while (true) {
                if (i + 4 < end) LOADQ(B, i + 4);
                COMPQ(A, i);
                i += 4;
                if (i >= end) break;
                if (i + 4 < end) LOADQ(A, i + 4);
                COMPQ(B, i);
                i += 4;
                if (i >= end) break;
            }
        }

        int r0 = __builtin_amdgcn_cvt_pk_fp8_f32(a01.x, a01.y, 0, false);
        r0 = __builtin_amdgcn_cvt_pk_fp8_f32(a23.x, a23.y, r0, true);
        int r1 = __builtin_amdgcn_cvt_pk_fp8_f32(a45.x, a45.y, 0, false);
        r1 = __builtin_amdgcn_cvt_pk_fp8_f32(a67.x, a67.y, r1, true);
        *(uint2*)(attended + (size_t)d * 128 + sub * 8) = make_uint2((uint)r0, (uint)r1);
    }

    __shared__ float sl[256];
    sl[t] = lsum;
    __syncthreads();
    if (t < 8) {
        float L = 0.f;
        for (int base = 0; base < 256; base += 16)
            L += sl[base + 2 * t] + sl[base + 2 * t + 1];
        block_l[blockIdx.x * 8 + t] = 0.5f * L;
    }
}

// ============ gemm_out: W in regs; fp8 attended input; folds L-reduction ============
__global__ __launch_bounds__(256) void gemm_out(
    const uchar* __restrict__ A, const ushort* __restrict__ wall,
    const float* __restrict__ bias, const float* __restrict__ res,
    const float* __restrict__ block_l,
    float* __restrict__ C, int M)
{
    __shared__ __align__(16) char sm[34816];
    ushort (*As)[136] = (ushort(*)[136])sm;
    ushort (*Cs)[136] = (ushort(*)[136])(sm + 17408);
    __shared__ float invl_s[8];
    __shared__ float sl[256];

    const int t = threadIdx.x;

    // fold reduce_l (per-block redundant, L2-hot)
    {
        float l = 0.f;
        for (int i = t; i < FU_BLOCKS * 8; i += 256) l += block_l[i];
        sl[t] = l;
        __syncthreads();
        if (t < 8) {
            float L = 0.f;
            for (int j = t; j < 256; j += 8) L += sl[j];
            invl_s[t] = 1.0f / L;
        }
        __syncthreads();
    }

    const int lane = t & 63;
    const int w = t >> 6;
    const int m_l = lane & 15;
    const int q_l = lane >> 4;

    short8 wfr[2][4];
    {
        const ushort* wb = wall + (size_t)(384 + 2 * w * 16 + m_l) * HCH + q_l * 8;
#pragma unroll
        for (int tlj = 0; tlj < 2; tlj++)
#pragma unroll
            for (int ks = 0; ks < 4; ks++)
                wfr[tlj][ks] = *(const short8*)(wb + (size_t)tlj * 16 * HCH + ks * 32);
    }

    const int arow = t >> 4, au = t & 15;          // A-stage: 16 rows/pass, 8 ch per thread
    const float invl_a = invl_s[au >> 1];
    const int eu = t & 31;
    const float4 eb = *(const float4*)(bias + eu * 4);

    uint2 a2[4];
    {
        const int mb = blockIdx.x * 64;
#pragma unroll
        for (int i = 0; i < 4; i++) {
            int g = mb + arow + i * 16;
            a2[i] = make_uint2(0, 0);
            if (g < M) a2[i] = *(const uint2*)(A + (size_t)g * 128 + au * 8);
        }
    }

    for (int tile = blockIdx.x; tile < GTILES; tile += GO_BLOCKS) {
        const int mb = tile * 64;
#pragma unroll
        for (int i = 0; i < 4; i++) {
            floatx2 f01 = __builtin_amdgcn_cvt_pk_f32_fp8((int)a2[i].x, false);
            floatx2 f23 = __builtin_amdgcn_cvt_pk_f32_fp8((int)a2[i].x, true);
            floatx2 f45 = __builtin_amdgcn_cvt_pk_f32_fp8((int)a2[i].y, false);
            floatx2 f67 = __builtin_amdgcn_cvt_pk_f32_fp8((int)a2[i].y, true);
            uint4 o;
            o.x = (uint)f2bf(f01.x * invl_a) | ((uint)f2bf(f01.y * invl_a) << 16);
            o.y = (uint)f2bf(f23.x * invl_a) | ((uint)f2bf(f23.y * invl_a) << 16);
            o.z = (uint)f2bf(f45.x * invl_a) | ((uint)f2bf(f45.y * invl_a) << 16);
            o.w = (uint)f2bf(f67.x * invl_a) | ((uint)f2bf(f67.y * invl_a) << 16);
            *(uint4*)(&As[arow + i * 16][au * 8]) = o;
        }
        const int ntile = tile + GO_BLOCKS;
        if (ntile < GTILES) {
            const int nmb = ntile * 64;
#pragma unroll
            for (int i = 0; i < 4; i++) {
                int g = nmb + arow + i * 16;
                uint2 v = make_uint2(0, 0);
                if (g < M) v = *(const uint2*)(A + (size_t)g * 128 + au * 8);
                a2[i] = v;
            }
        }
        __syncthreads();

        floatx4 acc[4][2];
#pragma unroll
        for (int ms = 0; ms < 4; ms++) {
            acc[ms][0] = (floatx4){0.f, 0.f, 0.f, 0.f};
            acc[ms][1] = (floatx4){0.f, 0.f, 0.f, 0.f};
        }
#pragma unroll
        for (int ks = 0; ks < 4; ks++) {
#pragma unroll
            for (int ms = 0; ms < 4; ms++) {
                short8 af = *(const short8*)(&As[ms * 16 + m_l][ks * 32 + q_l * 8]);
                acc[ms][0] = __builtin_amdgcn_mfma_f32_16x16x32_bf16(af, wfr[0][ks], acc[ms][0], 0, 0, 0);
                acc[ms][1] = __builtin_amdgcn_mfma_f32_16x16x32_bf16(af, wfr[1][ks], acc[ms][1], 0, 0, 0);
            }
        }
#pragma unroll
        for (int ms = 0; ms < 4; ms++)
#pragma unroll
            for (int tlj = 0; tlj < 2; tlj++)
#pragma unroll
                for (int r = 0; r < 4; r++)
                    Cs[ms * 16 + q_l * 4 + r][(2 * w + tlj) * 16 + m_l] = f2bf(acc[ms][tlj][r]);
        __syncthreads();

#pragma unroll
        for (int i = 0; i < 8; i++) {
            int row = (t >> 5) + i * 8;
            int g = mb + row;
            if (g < M) {
                uint2 c = *(const uint2*)(&Cs[row][eu * 4]);
                float4 r4 = *(const float4*)(res + (size_t)g * HCH + eu * 4);
                float4 o;
                o.x = bflo(c.x) + eb.x + r4.x;
                o.y = bfhi(c.x) + eb.y + r4.y;
                o.z = bflo(c.y) + eb.z + r4.z;
                o.w = bfhi(c.y) + eb.w + r4.w;
                *(float4*)(C + (size_t)g * HCH + eu * 4) = o;
            }
        }
        __syncthreads();
    }
}

extern "C" void kernel_launch(void* const* d_in, const int* in_sizes, int n_in,
                              void* d_out, int out_size, void* d_ws, size_t ws_size,
                              hipStream_t stream)
{
    const float* x  = (const float*)d_in[0];
    const int* eidx = (const int*)d_in[1];
    const float* Wq = (const float*)d_in[2];
    const float* bq = (const float*)d_in[3];
    const float* Wk = (const float*)d_in[4];
    const float* bk = (const float*)d_in[5];
    const float* Wv = (const float*)d_in[6];
    const float* bv = (const float*)d_in[7];
    const float* Wo = (const float*)d_in[8];
    const float* bo = (const float*)d_in[9];
    float* out = (float*)d_out;

    char* ws = (char*)d_ws;
    constexpr size_t SZ_F8  = (size_t)N_NODES * HCH;          // 12.8 MB fp8 per buffer
    constexpr size_t SZ_PS  = (size_t)E_EDGES * sizeof(int);  // 6.4 MB
    constexpr size_t SZ_TMP = (size_t)E_EDGES * sizeof(uint); // 6.4 MB packed
    size_t off = 0;
    uchar* qe = (uchar*)(ws + off); off += SZ_F8;
    uchar* kb = (uchar*)(ws + off); off += SZ_F8;
    uchar* vb = (uchar*)(ws + off); off += SZ_F8;
    uchar* attended = (uchar*)(ws + off); off += SZ_F8;
    int*    psrc     = (int*)(ws + off);    off += SZ_PS;
    uint*   tmp      = (uint*)(ws + off);   off += SZ_TMP;
    int*    offsets  = (int*)(ws + off);    off += ((size_t)N_NODES + 1) * 4 + 8;
    int*    bucket_total  = (int*)(ws + off); off += (NBUCK + 1) * 4;
    int*    bucket_start  = (int*)(ws + off); off += (NBUCK + 1) * 4;
    int*    bucket_cursor = (int*)(ws + off); off += (NBUCK + 1) * 4;
    float*  block_l   = (float*)(ws + off); off += (size_t)FU_BLOCKS * 8 * sizeof(float);
    ushort* wall = (ushort*)(ws + off); off += (size_t)512 * HCH * 2;
    const int* src = eidx;
    const int* dst = eidx + E_EDGES;

    dim3 blk(256);

    hipMemsetAsync(bucket_total, 0, (NBUCK + 1) * 4, stream);
    prep_hist<<<S1_GRID + 32, blk, 0, stream>>>(Wq, Wk, Wv, Wo, wall, dst, bucket_total);
    bucket_scan<<<1, 512, 0, stream>>>(bucket_total, bucket_start, bucket_cursor, offsets);

    mega_qkv_scatter<<<S1_GRID + GQ_BLOCKS, blk, 0, stream>>>(
        x, wall, bq, bk, bv, qe, kb, vb, src, dst, bucket_cursor, tmp, N_NODES);

    sort_scatter2<<<NBUCK, blk, 0, stream>>>(tmp, bucket_start, psrc, offsets);

    edge_fused<<<FU_BLOCKS, blk, 0, stream>>>(qe, kb, vb, psrc, offsets, attended, block_l);

    gemm_out<<<GO_BLOCKS, blk, 0, stream>>>(attended, wall, bo, x, block_l, out, N_NODES);
}

// Round 9
// 281.390 us; speedup vs baseline: 1.4607x; 1.0404x over previous
//
#include <hip/hip_runtime.h>
#include <cstdint>
#include <cstddef>

#define N_NODES 100000
#define E_EDGES 1600000
#define HCH 128
#define NHEADS 8
#define HDIM 16

typedef unsigned int uint;
typedef unsigned short ushort;
typedef unsigned char uchar;
typedef __attribute__((ext_vector_type(8))) short short8;
typedef __attribute__((ext_vector_type(4))) float floatx4;
typedef __attribute__((ext_vector_type(2))) float floatx2;

constexpr int GTILES = (N_NODES + 63) / 64;   // 1563

__device__ __forceinline__ ushort f2bf(float f) {
    uint u = __float_as_uint(f);
    u = (u + 0x7fff + ((u >> 16) & 1)) >> 16;
    return (ushort)u;
}
__device__ __forceinline__ float bflo(uint p) { return __uint_as_float(p << 16); }
__device__ __forceinline__ float bfhi(uint p) { return __uint_as_float(p & 0xffff0000u); }

// ================= sort constants =================
constexpr int BSHIFT = 8;
constexpr int NBUCK  = ((N_NODES - 1) >> BSHIFT) + 1;   // 391
constexpr int S1_GRID = 256;
constexpr int S1_CH   = (E_EDGES + S1_GRID - 1) / S1_GRID;  // 6250
constexpr int S2_CAP  = 6144;
constexpr int FU_BLOCKS = 2048;
constexpr int FU_GROUPS = FU_BLOCKS * 16;
constexpr int GQ_BLOCKS = 1024;
constexpr int GO_BLOCKS = 1024;

// ============ prep_hist: blocks 0-255 = bucket_hist; 256-287 = prep_w ============
__global__ __launch_bounds__(256) void prep_hist(
    const float* __restrict__ Wq, const float* __restrict__ Wk,
    const float* __restrict__ Wv, const float* __restrict__ Wo,
    ushort* __restrict__ wall,
    const int* __restrict__ dst, int* __restrict__ bucket_total)
{
    const int t = threadIdx.x;
    const int bid = blockIdx.x;
    if (bid < S1_GRID) {
        __shared__ int cnt[NBUCK];
        for (int b = t; b < NBUCK; b += 256) cnt[b] = 0;
        __syncthreads();
        const int e0 = bid * S1_CH;
        const int n = min(S1_CH, E_EDGES - e0);
        for (int i = t; i < n; i += 256)
            atomicAdd(&cnt[dst[e0 + i] >> BSHIFT], 1);
        __syncthreads();
        for (int b = t; b < NBUCK; b += 256)
            if (cnt[b]) atomicAdd(&bucket_total[b], cnt[b]);
        return;
    }
    int r = (bid - S1_GRID) * 16 + (t >> 4);   // 0..511
    int k0 = (t & 15) * 8;
    const float* W;
    if (r < 128)      W = Wq;
    else if (r < 256) W = Wk;
    else if (r < 384) W = Wv;
    else              W = Wo;
    int n = r & 127;
    uint4 u;
    u.x = (uint)f2bf(W[(size_t)(k0 + 0) * HCH + n]) | ((uint)f2bf(W[(size_t)(k0 + 1) * HCH + n]) << 16);
    u.y = (uint)f2bf(W[(size_t)(k0 + 2) * HCH + n]) | ((uint)f2bf(W[(size_t)(k0 + 3) * HCH + n]) << 16);
    u.z = (uint)f2bf(W[(size_t)(k0 + 4) * HCH + n]) | ((uint)f2bf(W[(size_t)(k0 + 5) * HCH + n]) << 16);
    u.w = (uint)f2bf(W[(size_t)(k0 + 6) * HCH + n]) | ((uint)f2bf(W[(size_t)(k0 + 7) * HCH + n]) << 16);
    *(uint4*)(wall + (size_t)r * HCH + k0) = u;
}

__global__ __launch_bounds__(512) void bucket_scan(
    const int* __restrict__ bucket_total, int* __restrict__ bucket_start,
    int* __restrict__ bucket_cursor, int* __restrict__ offsets)
{
    __shared__ int s[512];
    const int t = threadIdx.x;
    int v = (t < NBUCK) ? bucket_total[t] : 0;
    s[t] = v;
    __syncthreads();
    for (int off = 1; off < 512; off <<= 1) {
        int a = (t >= off) ? s[t - off] : 0;
        __syncthreads();
        s[t] += a;
        __syncthreads();
    }
    int excl = s[t] - v;
    if (t < NBUCK) { bucket_start[t] = excl; bucket_cursor[t] = excl; }
    if (t == 0) { bucket_start[NBUCK] = E_EDGES; offsets[N_NODES] = E_EDGES; }
}

// ============ MEGA: blocks 0..255 = sort_scatter1; 256.. = gemm_qkv ============
// gemm: single pass over x; per A-tile loop q/k/v with W frags ping-ponged in regs.
#define LOADW(R, mode_) do { \
    const ushort* wb_ = wall + (size_t)((mode_) * 128 + 2 * w * 16 + m_l) * HCH + q_l * 8; \
    _Pragma("unroll") \
    for (int tlj = 0; tlj < 2; tlj++) \
        _Pragma("unroll") \
        for (int ks = 0; ks < 4; ks++) \
            R[tlj][ks] = *(const short8*)(wb_ + (size_t)tlj * 16 * HCH + ks * 32); \
} while (0)

#define GEMM_EPI(R, outp_, bias_) do { \
    floatx4 acc[4][2]; \
    _Pragma("unroll") \
    for (int ms = 0; ms < 4; ms++) { \
        acc[ms][0] = (floatx4){0.f, 0.f, 0.f, 0.f}; \
        acc[ms][1] = (floatx4){0.f, 0.f, 0.f, 0.f}; \
    } \
    _Pragma("unroll") \
    for (int ks = 0; ks < 4; ks++) { \
        _Pragma("unroll") \
        for (int ms = 0; ms < 4; ms++) { \
            short8 af = *(const short8*)(&As[ms * 16 + m_l][ks * 32 + q_l * 8]); \
            acc[ms][0] = __builtin_amdgcn_mfma_f32_16x16x32_bf16(af, R[0][ks], acc[ms][0], 0, 0, 0); \
            acc[ms][1] = __builtin_amdgcn_mfma_f32_16x16x32_bf16(af, R[1][ks], acc[ms][1], 0, 0, 0); \
        } \
    } \
    _Pragma("unroll") \
    for (int ms = 0; ms < 4; ms++) \
        _Pragma("unroll") \
        for (int tlj = 0; tlj < 2; tlj++) \
            _Pragma("unroll") \
            for (int r = 0; r < 4; r++) \
                Cs[ms * 16 + q_l * 4 + r][(2 * w + tlj) * 16 + m_l] = f2bf(acc[ms][tlj][r]); \
    __syncthreads(); \
    _Pragma("unroll") \
    for (int i = 0; i < 4; i++) { \
        int row = (t >> 4) + i * 16; \
        int g = mb + row; \
        if (g < M) { \
            uint4 c = *(const uint4*)(&Cs[row][eu * 8]); \
            float4 b0 = *(const float4*)((bias_) + eu * 8); \
            float4 b1 = *(const float4*)((bias_) + eu * 8 + 4); \
            int r0 = __builtin_amdgcn_cvt_pk_fp8_f32(bflo(c.x) + b0.x, bfhi(c.x) + b0.y, 0, false); \
            r0 = __builtin_amdgcn_cvt_pk_fp8_f32(bflo(c.y) + b0.z, bfhi(c.y) + b0.w, r0, true); \
            int r1 = __builtin_amdgcn_cvt_pk_fp8_f32(bflo(c.z) + b1.x, bfhi(c.z) + b1.y, 0, false); \
            r1 = __builtin_amdgcn_cvt_pk_fp8_f32(bflo(c.w) + b1.z, bfhi(c.w) + b1.w, r1, true); \
            *(uint2*)((outp_) + (size_t)g * 128 + eu * 8) = make_uint2((uint)r0, (uint)r1); \
        } \
    } \
    __syncthreads(); \
} while (0)

__global__ __launch_bounds__(256) void mega_qkv_scatter(
    const float* __restrict__ A, const ushort* __restrict__ wall,
    const float* __restrict__ bq, const float* __restrict__ bk, const float* __restrict__ bv,
    uchar* __restrict__ qe, uchar* __restrict__ kb, uchar* __restrict__ vb,
    const int* __restrict__ src, const int* __restrict__ dst,
    int* __restrict__ bucket_cursor, uint* __restrict__ tmp,
    int M)
{
    __shared__ __align__(16) char sm[34816];
    const int t = threadIdx.x;
    const int bid = blockIdx.x;

    if (bid < S1_GRID) {
        // ---------------- sort_scatter1 ----------------
        int* cnt = (int*)sm;
        for (int b = t; b < NBUCK; b += 256) cnt[b] = 0;
        __syncthreads();
        const int e0 = bid * S1_CH;
        const int n = min(S1_CH, E_EDGES - e0);
        for (int i = t; i < n; i += 256)
            atomicAdd(&cnt[dst[e0 + i] >> BSHIFT], 1);
        __syncthreads();
        for (int b = t; b < NBUCK; b += 256) {
            int c = cnt[b];
            cnt[b] = c ? atomicAdd(&bucket_cursor[b], c) : 0;
        }
        __syncthreads();
        for (int i = t; i < n; i += 256) {
            int d = dst[e0 + i];
            int s = src[e0 + i];
            int pos = atomicAdd(&cnt[d >> BSHIFT], 1);
            tmp[pos] = (uint)s | ((uint)(d & 255) << 24);
        }
        return;
    }

    // ---------------- gemm_qkv: one x pass, 3 modes per tile ----------------
    ushort (*As)[136] = (ushort(*)[136])sm;
    ushort (*Cs)[136] = (ushort(*)[136])(sm + 17408);

    const int b = bid - S1_GRID;
    const int lane = t & 63;
    const int w = t >> 6;
    const int m_l = lane & 15;
    const int q_l = lane >> 4;
    const int eu = t & 15;
    const int arow = t >> 5, ac4 = t & 31;

    short8 wA[2][4], wB[2][4];

    // prologue A load
    float4 a4[8];
    {
        const int mb = b * 64;
#pragma unroll
        for (int i = 0; i < 8; i++) {
            int g = mb + arow + i * 8;
            a4[i] = make_float4(0.f, 0.f, 0.f, 0.f);
            if (g < M) a4[i] = *(const float4*)(A + (size_t)g * HCH + ac4 * 4);
        }
    }

    for (int tile = b; tile < GTILES; tile += GQ_BLOCKS) {
        const int mb = tile * 64;
        LOADW(wA, 0);
#pragma unroll
        for (int i = 0; i < 8; i++) {
            uint lo = (uint)f2bf(a4[i].x) | ((uint)f2bf(a4[i].y) << 16);
            uint hi = (uint)f2bf(a4[i].z) | ((uint)f2bf(a4[i].w) << 16);
            *(uint2*)(&As[arow + i * 8][ac4 * 4]) = make_uint2(lo, hi);
        }
        const int ntile = tile + GQ_BLOCKS;
        if (ntile < GTILES) {
            const int nmb = ntile * 64;
#pragma unroll
            for (int i = 0; i < 8; i++) {
                int g = nmb + arow + i * 8;
                float4 v = make_float4(0.f, 0.f, 0.f, 0.f);
                if (g < M) v = *(const float4*)(A + (size_t)g * HCH + ac4 * 4);
                a4[i] = v;
            }
        }
        __syncthreads();

        LOADW(wB, 1);
        GEMM_EPI(wA, qe, bq);
        LOADW(wA, 2);
        GEMM_EPI(wB, kb, bk);
        GEMM_EPI(wA, vb, bv);
    }
}

__global__ __launch_bounds__(256) void sort_scatter2(
    const uint* __restrict__ tmp, const int* __restrict__ bucket_start,
    int* __restrict__ psrc, int* __restrict__ offsets)
{
    __shared__ uint le[S2_CAP];
    __shared__ int cnt[256];
    __shared__ int s[256];
    __shared__ int cur[256];
    const int t = threadIdx.x;
    const int b = blockIdx.x;
    const int bstart = bucket_start[b];
    const int n = bucket_start[b + 1] - bstart;
    cnt[t] = 0;
    __syncthreads();
    for (int i = t; i < n; i += 256) {
        uint e = tmp[bstart + i];
        if (i < S2_CAP) le[i] = e;
        atomicAdd(&cnt[e >> 24], 1);
    }
    __syncthreads();
    int v = cnt[t];
    s[t] = v;
    __syncthreads();
    for (int off = 1; off < 256; off <<= 1) {
        int a = (t >= off) ? s[t - off] : 0;
        __syncthreads();
        s[t] += a;
        __syncthreads();
    }
    int excl = s[t] - v;
    int node = (b << BSHIFT) + t;
    if (node < N_NODES) offsets[node] = bstart + excl;
    cur[t] = excl;
    __syncthreads();
    for (int i = t; i < n; i += 256) {
        uint e = (i < S2_CAP) ? le[i] : tmp[bstart + i];
        int pos = bstart + atomicAdd(&cur[e >> 24], 1);
        psrc[pos] = (int)(e & 0x1FFFFu);
    }
}

// ============ FUSED segment reduce: one node per 16-lane group, 2-batch SWP ============
// w folded by 1/16 (exp bias -ln16) for fp8 range; per-head L via global atomics.
__device__ __forceinline__ float edge_w(
    uint2 e, floatx2 q0, floatx2 q1, floatx2 q2, floatx2 q3)
{
    floatx2 dp = q0 * __builtin_amdgcn_cvt_pk_f32_fp8((int)e.x, false);
    dp += q1 * __builtin_amdgcn_cvt_pk_f32_fp8((int)e.x, true);
    dp += q2 * __builtin_amdgcn_cvt_pk_f32_fp8((int)e.y, false);
    dp += q3 * __builtin_amdgcn_cvt_pk_f32_fp8((int)e.y, true);
    float p = dp.x + dp.y;
    p += __shfl_xor(p, 1);
    return __expf(p * 0.25f - 2.772588722f);   // exp(s)/16
}
__device__ __forceinline__ void edge_acc(
    uint2 e, float wgt, floatx2& a01, floatx2& a23, floatx2& a45, floatx2& a67)
{
    floatx2 wv = {wgt, wgt};
    a01 += wv * __builtin_amdgcn_cvt_pk_f32_fp8((int)e.x, false);
    a23 += wv * __builtin_amdgcn_cvt_pk_f32_fp8((int)e.x, true);
    a45 += wv * __builtin_amdgcn_cvt_pk_f32_fp8((int)e.y, false);
    a67 += wv * __builtin_amdgcn_cvt_pk_f32_fp8((int)e.y, true);
}

#define LOADQ(S, base) do { \
    int jj1 = min((base) + 1, end - 1); \
    int jj2 = min((base) + 2, end - 1); \
    int jj3 = min((base) + 3, end - 1); \
    int u0 = psrc[(base)], u1 = psrc[jj1], u2 = psrc[jj2], u3 = psrc[jj3]; \
    k##S##0 = *(const uint2*)(kb + (size_t)u0 * 128 + sub * 8); \
    k##S##1 = *(const uint2*)(kb + (size_t)u1 * 128 + sub * 8); \
    k##S##2 = *(const uint2*)(kb + (size_t)u2 * 128 + sub * 8); \
    k##S##3 = *(const uint2*)(kb + (size_t)u3 * 128 + sub * 8); \
    v##S##0 = *(const uint2*)(vb + (size_t)u0 * 128 + sub * 8); \
    v##S##1 = *(const uint2*)(vb + (size_t)u1 * 128 + sub * 8); \
    v##S##2 = *(const uint2*)(vb + (size_t)u2 * 128 + sub * 8); \
    v##S##3 = *(const uint2*)(vb + (size_t)u3 * 128 + sub * 8); \
} while (0)

#define COMPQ(S, base) do { \
    float w0 = edge_w(k##S##0, q0, q1, q2, q3); \
    float w1 = edge_w(k##S##1, q0, q1, q2, q3); \
    float w2 = edge_w(k##S##2, q0, q1, q2, q3); \
    float w3 = edge_w(k##S##3, q0, q1, q2, q3); \
    if ((base) + 1 >= end) w1 = 0.f; \
    if ((base) + 2 >= end) w2 = 0.f; \
    if ((base) + 3 >= end) w3 = 0.f; \
    lsum += w0 + w1 + w2 + w3; \
    edge_acc(v##S##0, w0, a01, a23, a45, a67); \
    edge_acc(v##S##1, w1, a01, a23, a45, a67); \
    edge_acc(v##S##2, w2, a01, a23, a45, a67); \
    edge_acc(v##S##3, w3, a01, a23, a45, a67); \
} while (0)

__global__ __launch_bounds__(256) void edge_fused(
    const uchar* __restrict__ qe, const uchar* __restrict__ kb, const uchar* __restrict__ vb,
    const int* __restrict__ psrc, const int* __restrict__ offsets,
    uchar* __restrict__ attended, float* __restrict__ head_l)
{
    const int t = threadIdx.x;
    const int sub = t & 15;
    const int gg0 = blockIdx.x * 16 + (t >> 4);

    float lsum = 0.f;

    for (int d = gg0; d < N_NODES; d += FU_GROUPS) {
        const int start = offsets[d];
        const int end   = offsets[d + 1];

        uint2 qw = *(const uint2*)(qe + (size_t)d * 128 + sub * 8);
        floatx2 q0 = __builtin_amdgcn_cvt_pk_f32_fp8((int)qw.x, false);
        floatx2 q1 = __builtin_amdgcn_cvt_pk_f32_fp8((int)qw.x, true);
        floatx2 q2 = __builtin_amdgcn_cvt_pk_f32_fp8((int)qw.y, false);
        floatx2 q3 = __builtin_amdgcn_cvt_pk_f32_fp8((int)qw.y, true);

        floatx2 a01 = {0.f, 0.f}, a23 = {0.f, 0.f}, a45 = {0.f, 0.f}, a67 = {0.f, 0.f};

        uint2 kA0, kA1, kA2, kA3, vA0, vA1, vA2, vA3;
        uint2 kB0, kB1, kB2, kB3, vB0, vB1, vB2, vB3;

        int i = start;
        if (i < end) {
            LOADQ(A, i);
            while (true) {
                if (i + 4 < end) LOADQ(B, i + 4);
                COMPQ(A, i);
                i += 4;
                if (i >= end) break;
                if (i + 4 < end) LOADQ(A, i + 4);
                COMPQ(B, i);
                i += 4;
                if (i >= end) break;
            }
        }

        int r0 = __builtin_amdgcn_cvt_pk_fp8_f32(a01.x, a01.y, 0, false);
        r0 = __builtin_amdgcn_cvt_pk_fp8_f32(a23.x, a23.y, r0, true);
        int r1 = __builtin_amdgcn_cvt_pk_fp8_f32(a45.x, a45.y, 0, false);
        r1 = __builtin_amdgcn_cvt_pk_fp8_f32(a67.x, a67.y, r1, true);
        *(uint2*)(attended + (size_t)d * 128 + sub * 8) = make_uint2((uint)r0, (uint)r1);
    }

    __shared__ float sl[256];
    sl[t] = lsum;
    __syncthreads();
    if (t < 8) {
        float L = 0.f;
        for (int base = 0; base < 256; base += 16)
            L += sl[base + 2 * t] + sl[base + 2 * t + 1];
        atomicAdd(&head_l[t], 0.5f * L);
    }
}

// ============ gemm_out: W in regs; fp8 attended; head_l direct ============
__global__ __launch_bounds__(256) void gemm_out(
    const uchar* __restrict__ A, const ushort* __restrict__ wall,
    const float* __restrict__ bias, const float* __restrict__ res,
    const float* __restrict__ head_l,
    float* __restrict__ C, int M)
{
    __shared__ __align__(16) char sm[34816];
    ushort (*As)[136] = (ushort(*)[136])sm;
    ushort (*Cs)[136] = (ushort(*)[136])(sm + 17408);
    __shared__ float invl_s[8];

    const int t = threadIdx.x;

    if (t < 8) invl_s[t] = 1.0f / head_l[t];
    __syncthreads();

    const int lane = t & 63;
    const int w = t >> 6;
    const int m_l = lane & 15;
    const int q_l = lane >> 4;

    short8 wfr[2][4];
    {
        const ushort* wb = wall + (size_t)(384 + 2 * w * 16 + m_l) * HCH + q_l * 8;
#pragma unroll
        for (int tlj = 0; tlj < 2; tlj++)
#pragma unroll
            for (int ks = 0; ks < 4; ks++)
                wfr[tlj][ks] = *(const short8*)(wb + (size_t)tlj * 16 * HCH + ks * 32);
    }

    const int arow = t >> 4, au = t & 15;
    const float invl_a = invl_s[au >> 1];
    const int eu = t & 31;
    const float4 eb = *(const float4*)(bias + eu * 4);

    uint2 a2[4];
    {
        const int mb = blockIdx.x * 64;
#pragma unroll
        for (int i = 0; i < 4; i++) {
            int g = mb + arow + i * 16;
            a2[i] = make_uint2(0, 0);
            if (g < M) a2[i] = *(const uint2*)(A + (size_t)g * 128 + au * 8);
        }
    }

    for (int tile = blockIdx.x; tile < GTILES; tile += GO_BLOCKS) {
        const int mb = tile * 64;
#pragma unroll
        for (int i = 0; i < 4; i++) {
            floatx2 f01 = __builtin_amdgcn_cvt_pk_f32_fp8((int)a2[i].x, false);
            floatx2 f23 = __builtin_amdgcn_cvt_pk_f32_fp8((int)a2[i].x, true);
            floatx2 f45 = __builtin_amdgcn_cvt_pk_f32_fp8((int)a2[i].y, false);
            floatx2 f67 = __builtin_amdgcn_cvt_pk_f32_fp8((int)a2[i].y, true);
            uint4 o;
            o.x = (uint)f2bf(f01.x * invl_a) | ((uint)f2bf(f01.y * invl_a) << 16);
            o.y = (uint)f2bf(f23.x * invl_a) | ((uint)f2bf(f23.y * invl_a) << 16);
            o.z = (uint)f2bf(f45.x * invl_a) | ((uint)f2bf(f45.y * invl_a) << 16);
            o.w = (uint)f2bf(f67.x * invl_a) | ((uint)f2bf(f67.y * invl_a) << 16);
            *(uint4*)(&As[arow + i * 16][au * 8]) = o;
        }
        const int ntile = tile + GO_BLOCKS;
        if (ntile < GTILES) {
            const int nmb = ntile * 64;
#pragma unroll
            for (int i = 0; i < 4; i++) {
                int g = nmb + arow + i * 16;
                uint2 v = make_uint2(0, 0);
                if (g < M) v = *(const uint2*)(A + (size_t)g * 128 + au * 8);
                a2[i] = v;
            }
        }
        __syncthreads();

        floatx4 acc[4][2];
#pragma unroll
        for (int ms = 0; ms < 4; ms++) {
            acc[ms][0] = (floatx4){0.f, 0.f, 0.f, 0.f};
            acc[ms][1] = (floatx4){0.f, 0.f, 0.f, 0.f};
        }
#pragma unroll
        for (int ks = 0; ks < 4; ks++) {
#pragma unroll
            for (int ms = 0; ms < 4; ms++) {
                short8 af = *(const short8*)(&As[ms * 16 + m_l][ks * 32 + q_l * 8]);
                acc[ms][0] = __builtin_amdgcn_mfma_f32_16x16x32_bf16(af, wfr[0][ks], acc[ms][0], 0, 0, 0);
                acc[ms][1] = __builtin_amdgcn_mfma_f32_16x16x32_bf16(af, wfr[1][ks], acc[ms][1], 0, 0, 0);
            }
        }
#pragma unroll
        for (int ms = 0; ms < 4; ms++)
#pragma unroll
            for (int tlj = 0; tlj < 2; tlj++)
#pragma unroll
                for (int r = 0; r < 4; r++)
                    Cs[ms * 16 + q_l * 4 + r][(2 * w + tlj) * 16 + m_l] = f2bf(acc[ms][tlj][r]);
        __syncthreads();

#pragma unroll
        for (int i = 0; i < 8; i++) {
            int row = (t >> 5) + i * 8;
            int g = mb + row;
            if (g < M) {
                uint2 c = *(const uint2*)(&Cs[row][eu * 4]);
                float4 r4 = *(const float4*)(res + (size_t)g * HCH + eu * 4);
                float4 o;
                o.x = bflo(c.x) + eb.x + r4.x;
                o.y = bfhi(c.x) + eb.y + r4.y;
                o.z = bflo(c.y) + eb.z + r4.z;
                o.w = bfhi(c.y) + eb.w + r4.w;
                *(float4*)(C + (size_t)g * HCH + eu * 4) = o;
            }
        }
        __syncthreads();
    }
}

extern "C" void kernel_launch(void* const* d_in, const int* in_sizes, int n_in,
                              void* d_out, int out_size, void* d_ws, size_t ws_size,
                              hipStream_t stream)
{
    const float* x  = (const float*)d_in[0];
    const int* eidx = (const int*)d_in[1];
    const float* Wq = (const float*)d_in[2];
    const float* bq = (const float*)d_in[3];
    const float* Wk = (const float*)d_in[4];
    const float* bk = (const float*)d_in[5];
    const float* Wv = (const float*)d_in[6];
    const float* bv = (const float*)d_in[7];
    const float* Wo = (const float*)d_in[8];
    const float* bo = (const float*)d_in[9];
    float* out = (float*)d_out;

    char* ws = (char*)d_ws;
    constexpr size_t SZ_F8  = (size_t)N_NODES * HCH;          // 12.8 MB fp8 per buffer
    constexpr size_t SZ_PS  = (size_t)E_EDGES * sizeof(int);  // 6.4 MB
    constexpr size_t SZ_TMP = (size_t)E_EDGES * sizeof(uint); // 6.4 MB packed
    size_t off = 0;
    uchar* qe = (uchar*)(ws + off); off += SZ_F8;
    uchar* kb = (uchar*)(ws + off); off += SZ_F8;
    uchar* vb = (uchar*)(ws + off); off += SZ_F8;
    uchar* attended = (uchar*)(ws + off); off += SZ_F8;
    int*    psrc     = (int*)(ws + off);    off += SZ_PS;
    uint*   tmp      = (uint*)(ws + off);   off += SZ_TMP;
    int*    offsets  = (int*)(ws + off);    off += ((size_t)N_NODES + 1) * 4 + 8;
    int*    bucket_total  = (int*)(ws + off); off += (NBUCK + 1) * 4;
    float*  head_l        = (float*)(ws + off); off += 8 * 4;
    int*    bucket_start  = (int*)(ws + off); off += (NBUCK + 1) * 4;
    int*    bucket_cursor = (int*)(ws + off); off += (NBUCK + 1) * 4;
    ushort* wall = (ushort*)(ws + off); off += (size_t)512 * HCH * 2;
    const int* src = eidx;
    const int* dst = eidx + E_EDGES;

    dim3 blk(256);

    // zero bucket_total + head_l in one shot (contiguous)
    hipMemsetAsync(bucket_total, 0, (NBUCK + 1) * 4 + 8 * 4, stream);
    prep_hist<<<S1_GRID + 32, blk, 0, stream>>>(Wq, Wk, Wv, Wo, wall, dst, bucket_total);
    bucket_scan<<<1, 512, 0, stream>>>(bucket_total, bucket_start, bucket_cursor, offsets);

    mega_qkv_scatter<<<S1_GRID + GQ_BLOCKS, blk, 0, stream>>>(
        x, wall, bq, bk, bv, qe, kb, vb, src, dst, bucket_cursor, tmp, N_NODES);

    sort_scatter2<<<NBUCK, blk, 0, stream>>>(tmp, bucket_start, psrc, offsets);

    edge_fused<<<FU_BLOCKS, blk, 0, stream>>>(qe, kb, vb, psrc, offsets, attended, head_l);

    gemm_out<<<GO_BLOCKS, blk, 0, stream>>>(attended, wall, bo, x, head_l, out, N_NODES);
}